// Round 8
// baseline (930.744 us; speedup 1.0000x reference)
//
#include <hip/hip_runtime.h>

#define NNODES 20000
#define NEDGES 320000
#define HID 128
#define NL 4

constexpr int NH = NNODES * HID;
#define BN_INV (1.0f / (float)NNODES)
#define XPAD 132
#define ROWS 20          // rows per GEMM block; 20000/20 = 1000 blocks (4/CU)
#define RPT 5            // rows per thread: 4 row-groups (waves) * 5
// thread tile: 5 rows x 2 cols; 64 col-groups (tid&63) x 4 row-groups (tid>>6)

typedef unsigned short u16;
typedef unsigned int u32;

// ---------------------------------------------------------------- bf16 utils
__device__ __forceinline__ float bf2f(u32 lo16) {
    union { u32 u; float f; } c; c.u = lo16 << 16; return c.f;
}
__device__ __forceinline__ u16 f2bf(float f) {
    union { float f; u32 u; } c; c.f = f;
    u32 r = c.u + 0x7FFFu + ((c.u >> 16) & 1u);
    return (u16)(r >> 16);
}
__device__ __forceinline__ u32 pack2(float a, float b) {
    return (u32)f2bf(a) | ((u32)f2bf(b) << 16);
}

// ---------------------------------------------------------------- embed
__global__ __launch_bounds__(256) void k_embed(const float* __restrict__ h,
    const float* __restrict__ ew, const float* __restrict__ eb,
    float* __restrict__ x, u16* __restrict__ xh)
{
    int i = blockIdx.x * 256 + threadIdx.x;          // exactly NH threads
    int nrow = i >> 7, j = i & 127;
    float v = fmaf(h[nrow * 2], ew[j], fmaf(h[nrow * 2 + 1], ew[HID + j], eb[j]));
    x[i] = v;
    if (xh) xh[i] = f2bf(v);
}

// ---------------------------------------------------------------- CSR build
__global__ __launch_bounds__(256) void k_hist(const int* __restrict__ dst,
    int* __restrict__ deg)
{
    int e = blockIdx.x * 256 + threadIdx.x;          // exactly NEDGES threads
    atomicAdd(&deg[dst[e]], 1);
}

__global__ __launch_bounds__(1024) void k_scan(const int* __restrict__ deg,
    int* __restrict__ off)
{
    __shared__ int part[1024];
    const int t = threadIdx.x;
    const int lo = t * 20, hi = min(lo + 20, NNODES);
    int s = 0;
    for (int i = lo; i < hi; ++i) s += deg[i];
    part[t] = s;
    __syncthreads();
    for (int d = 1; d < 1024; d <<= 1) {
        int v = (t >= d) ? part[t - d] : 0;
        __syncthreads();
        part[t] += v;
        __syncthreads();
    }
    int base = part[t] - s;                          // exclusive prefix
    for (int i = lo; i < hi; ++i) { off[i] = base; base += deg[i]; }
}

__global__ __launch_bounds__(256) void k_fill(const int* __restrict__ src,
    const int* __restrict__ dst, int* __restrict__ off,
    u16* __restrict__ eidx, int* __restrict__ epos)
{
    int e = blockIdx.x * 256 + threadIdx.x;          // exactly NEDGES threads
    int p = atomicAdd(&off[dst[e]], 1);
    eidx[p] = (u16)src[e];
    epos[p] = e;
}

// --------------------------------------------- stat helpers (device)
// mapping A: 64 col-groups x 2 cols (GEMM kernels) — no shuffle needed
__device__ __forceinline__ void stat_reduce2(float s0, float s1, float q0, float q1,
    int j0, float* ls, float* lq, float* sums)
{
    atomicAdd(&ls[j0], s0);     atomicAdd(&ls[j0 + 1], s1);
    atomicAdd(&lq[j0], q0);     atomicAdd(&lq[j0 + 1], q1);
    __syncthreads();
    if (threadIdx.x < 128) {
        atomicAdd(&sums[threadIdx.x], ls[threadIdx.x]);
        atomicAdd(&sums[128 + threadIdx.x], lq[threadIdx.x]);
    }
}

// mapping B: 32 col-groups x 4 cols (k_app_stat)
__device__ __forceinline__ void stat_reduce4(float* s4, float* q4, int j0,
    float* ls, float* lq, float* sums)
{
    const int lane = threadIdx.x & 63;
    #pragma unroll
    for (int c = 0; c < 4; ++c) {
        s4[c] += __shfl_xor(s4[c], 32);
        q4[c] += __shfl_xor(q4[c], 32);
    }
    if (lane < 32) {
        #pragma unroll
        for (int c = 0; c < 4; ++c) {
            atomicAdd(&ls[j0 + c], s4[c]);
            atomicAdd(&lq[j0 + c], q4[c]);
        }
    }
    __syncthreads();
    if (threadIdx.x < 128) {
        atomicAdd(&sums[threadIdx.x], ls[threadIdx.x]);
        atomicAdd(&sums[128 + threadIdx.x], lq[threadIdx.x]);
    }
}

// --------------------------- GEMM core (Xs staged) : 2 cols x 5 rows / thread
#define GEMM_CORE_1(W, acc)                                                    \
    _Pragma("unroll 8")                                                        \
    for (int k = 0; k < 128; ++k) {                                            \
        const float2 w2 = *reinterpret_cast<const float2*>(W + k * HID + j0);  \
        _Pragma("unroll")                                                      \
        for (int r = 0; r < RPT; ++r) {                                        \
            const float xv = Xs[r0 + r][k];                                    \
            acc[r][0] = fmaf(xv, w2.x, acc[r][0]);                             \
            acc[r][1] = fmaf(xv, w2.y, acc[r][1]);                             \
        }                                                                      \
    }

// ---------------- fused gather + GEMM(W1) + stats: u = t@W1+b1, t gathered
__global__ __launch_bounds__(256) void k_gemm_gather_stat(
    const float* __restrict__ x, const u16* __restrict__ xh,
    const int* __restrict__ off, const u16* __restrict__ eidx,
    const float* __restrict__ eps, int layer,
    const float* __restrict__ W, const float* __restrict__ bias,
    float* __restrict__ Cm, float* __restrict__ sums)
{
    __shared__ float Xs[ROWS][XPAD];
    __shared__ float ls[128], lq[128];
    const int tid = threadIdx.x;
    const int br = blockIdx.x * ROWS;
    if (tid < 128) { ls[tid] = 0.f; lq[tid] = 0.f; }
    const float e1 = 1.0f + eps[layer];
    // ---- gather staging: 16 groups of 16 lanes; group g does rows g, g+16
    {
        const int g = tid >> 4, l = tid & 15;
        for (int rr = g; rr < ROWS; rr += 16) {
            const int n = br + rr;
            const int start = n ? off[n - 1] : 0;
            const int end = off[n];
            const float4* xr = reinterpret_cast<const float4*>(x + (size_t)n * HID + l * 8);
            float4 a0 = xr[0], a1 = xr[1];
            float acc[8] = {a0.x * e1, a0.y * e1, a0.z * e1, a0.w * e1,
                            a1.x * e1, a1.y * e1, a1.z * e1, a1.w * e1};
            if (xh) {
                int e = start;
                for (; e + 1 < end; e += 2) {
                    const uint4 v0 = *reinterpret_cast<const uint4*>(xh + (size_t)eidx[e] * HID + l * 8);
                    const uint4 v1 = *reinterpret_cast<const uint4*>(xh + (size_t)eidx[e + 1] * HID + l * 8);
                    acc[0] += bf2f(v0.x & 0xffff) + bf2f(v1.x & 0xffff);
                    acc[1] += bf2f(v0.x >> 16)    + bf2f(v1.x >> 16);
                    acc[2] += bf2f(v0.y & 0xffff) + bf2f(v1.y & 0xffff);
                    acc[3] += bf2f(v0.y >> 16)    + bf2f(v1.y >> 16);
                    acc[4] += bf2f(v0.z & 0xffff) + bf2f(v1.z & 0xffff);
                    acc[5] += bf2f(v0.z >> 16)    + bf2f(v1.z >> 16);
                    acc[6] += bf2f(v0.w & 0xffff) + bf2f(v1.w & 0xffff);
                    acc[7] += bf2f(v0.w >> 16)    + bf2f(v1.w >> 16);
                }
                if (e < end) {
                    const uint4 v0 = *reinterpret_cast<const uint4*>(xh + (size_t)eidx[e] * HID + l * 8);
                    acc[0] += bf2f(v0.x & 0xffff); acc[1] += bf2f(v0.x >> 16);
                    acc[2] += bf2f(v0.y & 0xffff); acc[3] += bf2f(v0.y >> 16);
                    acc[4] += bf2f(v0.z & 0xffff); acc[5] += bf2f(v0.z >> 16);
                    acc[6] += bf2f(v0.w & 0xffff); acc[7] += bf2f(v0.w >> 16);
                }
            } else {
                for (int e = start; e < end; ++e) {
                    const float4* vr = reinterpret_cast<const float4*>(x + (size_t)eidx[e] * HID + l * 8);
                    float4 v0 = vr[0], v1 = vr[1];
                    acc[0] += v0.x; acc[1] += v0.y; acc[2] += v0.z; acc[3] += v0.w;
                    acc[4] += v1.x; acc[5] += v1.y; acc[6] += v1.z; acc[7] += v1.w;
                }
            }
            *reinterpret_cast<float4*>(&Xs[rr][l * 8])     = make_float4(acc[0], acc[1], acc[2], acc[3]);
            *reinterpret_cast<float4*>(&Xs[rr][l * 8 + 4]) = make_float4(acc[4], acc[5], acc[6], acc[7]);
        }
    }
    __syncthreads();
    const int j0 = (tid & 63) * 2;
    const int r0 = (tid >> 6) * RPT;
    float acc[RPT][2];
    #pragma unroll
    for (int r = 0; r < RPT; ++r) { acc[r][0] = 0.f; acc[r][1] = 0.f; }
    GEMM_CORE_1(W, acc)
    const float2 bv = *reinterpret_cast<const float2*>(bias + j0);
    float s0 = 0.f, s1 = 0.f, q0 = 0.f, q1 = 0.f;
    #pragma unroll
    for (int r = 0; r < RPT; ++r) {
        float v0 = acc[r][0] + bv.x, v1 = acc[r][1] + bv.y;
        s0 += v0; s1 += v1;
        q0 = fmaf(v0, v0, q0); q1 = fmaf(v1, v1, q1);
        *reinterpret_cast<float2*>(Cm + (size_t)(br + r0 + r) * HID + j0) =
            make_float2(v0, v1);
    }
    stat_reduce2(s0, s1, q0, q1, j0, ls, lq, sums);
}

// ---------------- v = relu(BN_sIn(u)) @ W2 + b2 ; stats(v) -> sums
__global__ __launch_bounds__(256) void k_gemm_bnin_stat(const float* __restrict__ X,
    const float* __restrict__ sIn, const float* __restrict__ g, const float* __restrict__ b,
    const float* __restrict__ W, const float* __restrict__ bias,
    float* __restrict__ Cm, float* __restrict__ sums)
{
    __shared__ float Xs[ROWS][XPAD];
    __shared__ float ac[256];
    __shared__ float ls[128], lq[128];
    const int tid = threadIdx.x;
    const int br = blockIdx.x * ROWS;
    if (tid < 128) {
        float m = sIn[tid] * BN_INV;
        float var = fmaf(-m, m, sIn[128 + tid] * BN_INV);
        float a = g[tid] * rsqrtf(var + 1e-5f);
        ac[tid] = a;
        ac[128 + tid] = fmaf(-m, a, b[tid]);
        ls[tid] = 0.f; lq[tid] = 0.f;
    }
    __syncthreads();
    #pragma unroll
    for (int it = 0; it < 3; ++it) {
        int f = tid + it * 256;
        if (f < ROWS * 32) {
            int r = f >> 5, kq = (f & 31) << 2;
            float4 v = *reinterpret_cast<const float4*>(X + (size_t)(br + r) * HID + kq);
            v.x = fmaxf(fmaf(ac[kq + 0], v.x, ac[128 + kq + 0]), 0.f);
            v.y = fmaxf(fmaf(ac[kq + 1], v.y, ac[128 + kq + 1]), 0.f);
            v.z = fmaxf(fmaf(ac[kq + 2], v.z, ac[128 + kq + 2]), 0.f);
            v.w = fmaxf(fmaf(ac[kq + 3], v.w, ac[128 + kq + 3]), 0.f);
            *reinterpret_cast<float4*>(&Xs[r][kq]) = v;
        }
    }
    __syncthreads();
    const int j0 = (tid & 63) * 2;
    const int r0 = (tid >> 6) * RPT;
    float acc[RPT][2];
    #pragma unroll
    for (int r = 0; r < RPT; ++r) { acc[r][0] = 0.f; acc[r][1] = 0.f; }
    GEMM_CORE_1(W, acc)
    const float2 bv = *reinterpret_cast<const float2*>(bias + j0);
    float s0 = 0.f, s1 = 0.f, q0 = 0.f, q1 = 0.f;
    #pragma unroll
    for (int r = 0; r < RPT; ++r) {
        float v0 = acc[r][0] + bv.x, v1 = acc[r][1] + bv.y;
        s0 += v0; s1 += v1;
        q0 = fmaf(v0, v0, q0); q1 = fmaf(v1, v1, q1);
        *reinterpret_cast<float2*>(Cm + (size_t)(br + r0 + r) * HID + j0) =
            make_float2(v0, v1);
    }
    stat_reduce2(s0, s1, q0, q1, j0, ls, lq, sums);
}

// --------------------------------- dual-GEMM body -> bf16 A,B outputs
#define HEAD_GEMM_BODY(W1, b1, A, Bm)                                          \
    const int j0 = (tid & 63) * 2;                                             \
    const int r0 = (tid >> 6) * RPT;                                           \
    float accA[RPT][2], accB[RPT][2];                                          \
    _Pragma("unroll")                                                          \
    for (int r = 0; r < RPT; ++r) {                                            \
        accA[r][0] = 0.f; accA[r][1] = 0.f;                                    \
        accB[r][0] = 0.f; accB[r][1] = 0.f;                                    \
    }                                                                          \
    _Pragma("unroll 4")                                                        \
    for (int k = 0; k < 128; ++k) {                                            \
        const float2 wa = *reinterpret_cast<const float2*>(W1 + k * HID + j0); \
        const float2 wb = *reinterpret_cast<const float2*>(W1 + (HID + k) * HID + j0);\
        _Pragma("unroll")                                                      \
        for (int r = 0; r < RPT; ++r) {                                        \
            const float xv = Xs[r0 + r][k];                                    \
            accA[r][0] = fmaf(xv, wa.x, accA[r][0]);                           \
            accA[r][1] = fmaf(xv, wa.y, accA[r][1]);                           \
            accB[r][0] = fmaf(xv, wb.x, accB[r][0]);                           \
            accB[r][1] = fmaf(xv, wb.y, accB[r][1]);                           \
        }                                                                      \
    }                                                                          \
    const float2 bv1 = *reinterpret_cast<const float2*>(b1 + j0);              \
    _Pragma("unroll")                                                          \
    for (int r = 0; r < RPT; ++r) {                                            \
        size_t rowoff = (size_t)(br + r0 + r) * HID + j0;                      \
        *reinterpret_cast<u32*>(A + rowoff)  = pack2(accA[r][0] + bv1.x,       \
                                                     accA[r][1] + bv1.y);      \
        *reinterpret_cast<u32*>(Bm + rowoff) = pack2(accB[r][0], accB[r][1]);  \
    }

// head 0: plain input staging
__global__ __launch_bounds__(256) void k_gemm_head(const float* __restrict__ X,
    const float* __restrict__ W1, const float* __restrict__ b1,
    u16* __restrict__ A, u16* __restrict__ Bm)
{
    __shared__ float Xs[ROWS][XPAD];
    const int tid = threadIdx.x;
    const int br = blockIdx.x * ROWS;
    #pragma unroll
    for (int it = 0; it < 3; ++it) {
        int f = tid + it * 256;
        if (f < ROWS * 32) {
            int r = f >> 5, kq = (f & 31) << 2;
            *reinterpret_cast<float4*>(&Xs[r][kq]) =
                *reinterpret_cast<const float4*>(X + (size_t)(br + r) * HID + kq);
        }
    }
    __syncthreads();
    HEAD_GEMM_BODY(W1, b1, A, Bm)
}

// heads 1..L: staging computes x += relu(gin(relu(app(v)))), writes x (+xh),
// and uses updated x as the GEMM input.
__global__ __launch_bounds__(256) void k_head_resid(const float* __restrict__ v,
    const float* __restrict__ s1, const float* __restrict__ ga, const float* __restrict__ ba,
    const float* __restrict__ s2, const float* __restrict__ gg, const float* __restrict__ bg,
    float* __restrict__ x, u16* __restrict__ xh,
    const float* __restrict__ W1, const float* __restrict__ b1,
    u16* __restrict__ A, u16* __restrict__ Bm)
{
    __shared__ float Xs[ROWS][XPAD];
    __shared__ float aca[256], acg[256];
    const int tid = threadIdx.x;
    const int br = blockIdx.x * ROWS;
    if (tid < 128) {
        float m = s1[tid] * BN_INV;
        float var = fmaf(-m, m, s1[128 + tid] * BN_INV);
        float a = ga[tid] * rsqrtf(var + 1e-5f);
        aca[tid] = a;
        aca[128 + tid] = fmaf(-m, a, ba[tid]);
        float m2 = s2[tid] * BN_INV;
        float var2 = fmaf(-m2, m2, s2[128 + tid] * BN_INV);
        float a2 = gg[tid] * rsqrtf(var2 + 1e-5f);
        acg[tid] = a2;
        acg[128 + tid] = fmaf(-m2, a2, bg[tid]);
    }
    __syncthreads();
    #pragma unroll
    for (int it = 0; it < 3; ++it) {
        int f = tid + it * 256;
        if (f < ROWS * 32) {
            int r = f >> 5, kq = (f & 31) << 2;
            size_t goff = (size_t)(br + r) * HID + kq;
            float4 vv = *reinterpret_cast<const float4*>(v + goff);
            float4 xv = *reinterpret_cast<const float4*>(x + goff);
            float t0 = fmaxf(fmaf(aca[kq + 0], vv.x, aca[128 + kq + 0]), 0.f);
            float t1 = fmaxf(fmaf(aca[kq + 1], vv.y, aca[128 + kq + 1]), 0.f);
            float t2 = fmaxf(fmaf(aca[kq + 2], vv.z, aca[128 + kq + 2]), 0.f);
            float t3 = fmaxf(fmaf(aca[kq + 3], vv.w, aca[128 + kq + 3]), 0.f);
            xv.x += fmaxf(fmaf(acg[kq + 0], t0, acg[128 + kq + 0]), 0.f);
            xv.y += fmaxf(fmaf(acg[kq + 1], t1, acg[128 + kq + 1]), 0.f);
            xv.z += fmaxf(fmaf(acg[kq + 2], t2, acg[128 + kq + 2]), 0.f);
            xv.w += fmaxf(fmaf(acg[kq + 3], t3, acg[128 + kq + 3]), 0.f);
            *reinterpret_cast<float4*>(x + goff) = xv;
            if (xh) *reinterpret_cast<uint2*>(xh + goff) =
                make_uint2(pack2(xv.x, xv.y), pack2(xv.z, xv.w));
            *reinterpret_cast<float4*>(&Xs[r][kq]) = xv;
        }
    }
    __syncthreads();
    HEAD_GEMM_BODY(W1, b1, A, Bm)
}

// ------------------------------------- stats of relu(app(v)) -> s2
// grid 1250 blocks x 16 rows: thread handles rows row0 and row0+8, 4 cols.
__global__ __launch_bounds__(256) void k_app_stat(const float* __restrict__ v,
    const float* __restrict__ s1, const float* __restrict__ g, const float* __restrict__ b,
    float* __restrict__ s2)
{
    __shared__ float ac[256];
    __shared__ float ls[128], lq[128];
    const int tid = threadIdx.x;
    if (tid < 128) {
        float m = s1[tid] * BN_INV;
        float var = fmaf(-m, m, s1[128 + tid] * BN_INV);
        float a = g[tid] * rsqrtf(var + 1e-5f);
        ac[tid] = a;
        ac[128 + tid] = fmaf(-m, a, b[tid]);
        ls[tid] = 0.f; lq[tid] = 0.f;
    }
    __syncthreads();
    const int j0 = (tid & 31) * 4;
    const int row0 = blockIdx.x * 16 + (tid >> 5);   // rows row0, row0+8
    float s4[4] = {0.f, 0.f, 0.f, 0.f}, q4[4] = {0.f, 0.f, 0.f, 0.f};
    #pragma unroll
    for (int rr = 0; rr < 2; ++rr) {
        const float4 v4 = *reinterpret_cast<const float4*>(
            v + (size_t)(row0 + rr * 8) * HID + j0);
        float w[4] = {v4.x, v4.y, v4.z, v4.w};
        #pragma unroll
        for (int c = 0; c < 4; ++c) {
            w[c] = fmaxf(fmaf(ac[j0 + c], w[c], ac[128 + j0 + c]), 0.f);
            s4[c] += w[c];
            q4[c] = fmaf(w[c], w[c], q4[c]);
        }
    }
    stat_reduce4(s4, q4, j0, ls, lq, s2);
}

// ---------------------------------------------------- edge head (dst-CSR)
// wave = 1 dst node; 16 lanes/edge (uint4 = 8 bf16), 4 edges in flight.
__global__ __launch_bounds__(256) void k_edge_csr(const u16* __restrict__ Ah,
    const u16* __restrict__ Bh, const int* __restrict__ off,
    const u16* __restrict__ eidx, const int* __restrict__ epos,
    const float* __restrict__ w2, const float* __restrict__ b2,
    float* __restrict__ out, int accumulate)
{
    const int wid = (blockIdx.x * 256 + threadIdx.x) >> 6;   // node; grid 5000
    const int lane = threadIdx.x & 63;
    const int q = lane >> 4, l = lane & 15;
    const int start = wid ? off[wid - 1] : 0;
    const int end = off[wid];
    const uint4 bb = *reinterpret_cast<const uint4*>(Bh + (size_t)wid * HID + l * 8);
    float b8[8] = {bf2f(bb.x & 0xffff), bf2f(bb.x >> 16),
                   bf2f(bb.y & 0xffff), bf2f(bb.y >> 16),
                   bf2f(bb.z & 0xffff), bf2f(bb.z >> 16),
                   bf2f(bb.w & 0xffff), bf2f(bb.w >> 16)};
    float w2f[16];
    #pragma unroll
    for (int t = 0; t < 4; ++t)
        *reinterpret_cast<float4*>(&w2f[t * 4]) =
            *reinterpret_cast<const float4*>(w2 + l * 16 + t * 4);
    const float bias0 = b2[0], bias1 = b2[1];
    for (int e = start + q; e < end; e += 4) {
        int s = eidx[e];
        const uint4 aa = *reinterpret_cast<const uint4*>(Ah + (size_t)s * HID + l * 8);
        float a8[8] = {bf2f(aa.x & 0xffff), bf2f(aa.x >> 16),
                       bf2f(aa.y & 0xffff), bf2f(aa.y >> 16),
                       bf2f(aa.z & 0xffff), bf2f(aa.z >> 16),
                       bf2f(aa.w & 0xffff), bf2f(aa.w >> 16)};
        float s0 = 0.f, s1 = 0.f;
        #pragma unroll
        for (int j = 0; j < 8; ++j) {
            float z = fmaxf(a8[j] + b8[j], 0.f);
            s0 = fmaf(z, w2f[j * 2], s0);
            s1 = fmaf(z, w2f[j * 2 + 1], s1);
        }
        #pragma unroll
        for (int m = 8; m >= 1; m >>= 1) {
            s0 += __shfl_xor(s0, m);
            s1 += __shfl_xor(s1, m);
        }
        if (l == 0) {
            int oe = epos[e];
            float o0 = s0 + bias0, o1 = s1 + bias1;
            if (accumulate) {
                out[oe * 2 + 0] += o0;
                out[oe * 2 + 1] += o1;
            } else {
                out[oe * 2 + 0] = o0;
                out[oe * 2 + 1] = o1;
            }
        }
    }
}

// ---------------------------------------------------------------- launch
extern "C" void kernel_launch(void* const* d_in, const int* in_sizes, int n_in,
                              void* d_out, int out_size, void* d_ws, size_t ws_size,
                              hipStream_t stream)
{
    const float* h        = (const float*)d_in[0];
    const int*   src      = (const int*)d_in[1];
    const int*   dst      = (const int*)d_in[2];
    const float* emb_w    = (const float*)d_in[3];
    const float* emb_b    = (const float*)d_in[4];
    const float* eps      = (const float*)d_in[5];
    const float* mlp_w1   = (const float*)d_in[6];
    const float* mlp_b1   = (const float*)d_in[7];
    const float* mlp_bn_g = (const float*)d_in[8];
    const float* mlp_bn_b = (const float*)d_in[9];
    const float* mlp_w2   = (const float*)d_in[10];
    const float* mlp_b2   = (const float*)d_in[11];
    const float* app_bn_g = (const float*)d_in[12];
    const float* app_bn_b = (const float*)d_in[13];
    const float* gin_bn_g = (const float*)d_in[14];
    const float* gin_bn_b = (const float*)d_in[15];
    const float* pred_w1  = (const float*)d_in[16];
    const float* pred_b1  = (const float*)d_in[17];
    const float* pred_w2  = (const float*)d_in[18];
    const float* pred_b2  = (const float*)d_in[19];
    float* out = (float*)d_out;

    float* ws   = (float*)d_ws;
    float* x    = ws;                       // [N,128] f32
    float* tmp1 = ws + NH;                  // [N,128] f32 (v)
    float* tmp2 = ws + 2 * (size_t)NH;      // [N,128] f32 (u), aliased by bf16 A,B
    float* sums = ws + 3 * (size_t)NH;      // [12][256]
    int*   off  = (int*)(sums + 12 * 256);  // [N]
    int*   deg  = off + NNODES;             // [N]
    int*   epos = deg + NNODES;             // [E]
    u16*   eidx = (u16*)(epos + NEDGES);    // [E]
    u16*   ah   = (u16*)tmp2;               // [N,128] bf16 (aliases tmp2 low half)
    u16*   bh   = ah + NH;                  // [N,128] bf16 (aliases tmp2 high half)
    size_t used_bytes = ((size_t)3 * NH + 12 * 256) * 4 + 2ull * NNODES * 4
                        + (size_t)NEDGES * 4 + (size_t)NEDGES * 2;
    u16* xh = (used_bytes + (size_t)NH * 2 <= ws_size) ? (eidx + NEDGES) : nullptr;

    const int NB = NH / 256;                    // 10000
    const int EB = NEDGES / 256;                // 1250
    const int GB = NNODES / ROWS;               // 1000
    const int ASB = NNODES / 16;                // 1250
    const int CEB = NNODES / 4;                 // 5000

    // ---- CSR build (graph static across layers)
    hipMemsetAsync(deg, 0, NNODES * sizeof(int), stream);
    hipMemsetAsync(sums, 0, 12 * 256 * sizeof(float), stream);
    k_hist<<<EB, 256, 0, stream>>>(dst, deg);
    k_scan<<<1, 1024, 0, stream>>>(deg, off);
    k_fill<<<EB, 256, 0, stream>>>(src, dst, off, eidx, epos);

    k_embed<<<NB, 256, 0, stream>>>(h, emb_w, emb_b, x, xh);

    // head 0
    k_gemm_head<<<GB, 256, 0, stream>>>(x, pred_w1, pred_b1, ah, bh);
    k_edge_csr<<<CEB, 256, 0, stream>>>(ah, bh, off, eidx, epos,
                                        pred_w2, pred_b2, out, 0);

    for (int i = 0; i < NL; ++i) {
        float* s0 = sums + (i * 3 + 0) * 256;
        float* s1 = sums + (i * 3 + 1) * 256;
        float* s2 = sums + (i * 3 + 2) * 256;

        // u = ((1+eps)x + gather) @ W1 + b1 ; stats(u) -> s0   [gather fused]
        k_gemm_gather_stat<<<GB, 256, 0, stream>>>(x, xh, off, eidx, eps, i,
                                                   mlp_w1 + (size_t)i * HID * HID,
                                                   mlp_b1 + i * HID, tmp2, s0);
        // v = relu(BN_s0(u)) @ W2 + b2 ; stats(v) -> s1
        k_gemm_bnin_stat<<<GB, 256, 0, stream>>>(tmp2, s0, mlp_bn_g + i * HID,
                                                 mlp_bn_b + i * HID,
                                                 mlp_w2 + (size_t)i * HID * HID,
                                                 mlp_b2 + i * HID, tmp1, s1);
        // stats(relu(BN_s1(v))) -> s2
        k_app_stat<<<ASB, 256, 0, stream>>>(tmp1, s1, app_bn_g + i * HID,
                                            app_bn_b + i * HID, s2);
        // x += relu(BN_s2(relu(BN_s1(v)))) fused into head GEMM staging;
        // A,B (bf16) overwrite tmp2 (u is dead). Per-block row ownership.
        k_head_resid<<<GB, 256, 0, stream>>>(tmp1, s1, app_bn_g + i * HID,
                                             app_bn_b + i * HID, s2,
                                             gin_bn_g + i * HID, gin_bn_b + i * HID,
                                             x, xh,
                                             pred_w1 + (size_t)(i + 1) * 256 * HID,
                                             pred_b1 + (i + 1) * HID, ah, bh);
        k_edge_csr<<<CEB, 256, 0, stream>>>(ah, bh, off, eidx, epos,
                                            pred_w2 + (i + 1) * HID * 2,
                                            pred_b2 + (i + 1) * 2, out, 1);
    }
}

// Round 9
// 839.704 us; speedup vs baseline: 1.1084x; 1.1084x over previous
//
#include <hip/hip_runtime.h>

#define NNODES 20000
#define NEDGES 320000
#define HID 128
#define NL 4

constexpr int NH = NNODES * HID;
#define BN_INV (1.0f / (float)NNODES)
#define XPAD 132
#define ROWS 40          // rows per GEMM block; 20000/40 = 500 blocks, 512 thr
#define RPT 5            // rows per thread: 8 row-groups (waves) * 5
// thread tile: 5 rows x 2 cols; 64 col-groups (tid&63) x 8 row-groups (tid>>6)

typedef unsigned short u16;
typedef unsigned int u32;

// ---------------------------------------------------------------- bf16 utils
__device__ __forceinline__ float bf2f(u32 lo16) {
    union { u32 u; float f; } c; c.u = lo16 << 16; return c.f;
}
__device__ __forceinline__ u16 f2bf(float f) {
    union { float f; u32 u; } c; c.f = f;
    u32 r = c.u + 0x7FFFu + ((c.u >> 16) & 1u);
    return (u16)(r >> 16);
}
__device__ __forceinline__ u32 pack2(float a, float b) {
    return (u32)f2bf(a) | ((u32)f2bf(b) << 16);
}

// ---------------------------------------------------------------- embed
__global__ __launch_bounds__(256) void k_embed(const float* __restrict__ h,
    const float* __restrict__ ew, const float* __restrict__ eb,
    float* __restrict__ x, u16* __restrict__ xh)
{
    int i = blockIdx.x * 256 + threadIdx.x;          // exactly NH threads
    int nrow = i >> 7, j = i & 127;
    float v = fmaf(h[nrow * 2], ew[j], fmaf(h[nrow * 2 + 1], ew[HID + j], eb[j]));
    x[i] = v;
    if (xh) xh[i] = f2bf(v);
}

// ---------------------------------------------------------------- CSR build
__global__ __launch_bounds__(256) void k_hist(const int* __restrict__ dst,
    int* __restrict__ deg)
{
    int e = blockIdx.x * 256 + threadIdx.x;          // exactly NEDGES threads
    atomicAdd(&deg[dst[e]], 1);
}

__global__ __launch_bounds__(1024) void k_scan(const int* __restrict__ deg,
    int* __restrict__ off)
{
    __shared__ int part[1024];
    const int t = threadIdx.x;
    const int lo = t * 20, hi = min(lo + 20, NNODES);
    int s = 0;
    for (int i = lo; i < hi; ++i) s += deg[i];
    part[t] = s;
    __syncthreads();
    for (int d = 1; d < 1024; d <<= 1) {
        int v = (t >= d) ? part[t - d] : 0;
        __syncthreads();
        part[t] += v;
        __syncthreads();
    }
    int base = part[t] - s;                          // exclusive prefix
    for (int i = lo; i < hi; ++i) { off[i] = base; base += deg[i]; }
}

__global__ __launch_bounds__(256) void k_fill(const int* __restrict__ src,
    const int* __restrict__ dst, int* __restrict__ off,
    u16* __restrict__ eidx, int* __restrict__ epos)
{
    int e = blockIdx.x * 256 + threadIdx.x;          // exactly NEDGES threads
    int p = atomicAdd(&off[dst[e]], 1);
    eidx[p] = (u16)src[e];
    epos[p] = e;
}

// ------------------------------------------- pull-mode aggregate (no atomics)
// 16 lanes/node; neighbor rows read from bf16 shadow xh (256B/row).
__global__ __launch_bounds__(256) void k_gather(const float* __restrict__ x,
    const u16* __restrict__ xh, const int* __restrict__ off,
    const u16* __restrict__ eidx, const float* __restrict__ eps, int layer,
    float* __restrict__ t)
{
    int tid = blockIdx.x * 256 + threadIdx.x;        // NNODES*16 threads
    int n = tid >> 4, l = tid & 15;
    int start = (n == 0) ? 0 : off[n - 1];
    int end = off[n];
    const float e1 = 1.0f + eps[layer];
    const float4* xr = reinterpret_cast<const float4*>(x + (size_t)n * HID + l * 8);
    float4 a0 = xr[0], a1 = xr[1];
    float acc[8] = {a0.x * e1, a0.y * e1, a0.z * e1, a0.w * e1,
                    a1.x * e1, a1.y * e1, a1.z * e1, a1.w * e1};
    if (xh) {
        int e = start;
        for (; e + 1 < end; e += 2) {
            const uint4 v0 = *reinterpret_cast<const uint4*>(xh + (size_t)eidx[e] * HID + l * 8);
            const uint4 v1 = *reinterpret_cast<const uint4*>(xh + (size_t)eidx[e + 1] * HID + l * 8);
            acc[0] += bf2f(v0.x & 0xffff) + bf2f(v1.x & 0xffff);
            acc[1] += bf2f(v0.x >> 16)    + bf2f(v1.x >> 16);
            acc[2] += bf2f(v0.y & 0xffff) + bf2f(v1.y & 0xffff);
            acc[3] += bf2f(v0.y >> 16)    + bf2f(v1.y >> 16);
            acc[4] += bf2f(v0.z & 0xffff) + bf2f(v1.z & 0xffff);
            acc[5] += bf2f(v0.z >> 16)    + bf2f(v1.z >> 16);
            acc[6] += bf2f(v0.w & 0xffff) + bf2f(v1.w & 0xffff);
            acc[7] += bf2f(v0.w >> 16)    + bf2f(v1.w >> 16);
        }
        if (e < end) {
            const uint4 v0 = *reinterpret_cast<const uint4*>(xh + (size_t)eidx[e] * HID + l * 8);
            acc[0] += bf2f(v0.x & 0xffff); acc[1] += bf2f(v0.x >> 16);
            acc[2] += bf2f(v0.y & 0xffff); acc[3] += bf2f(v0.y >> 16);
            acc[4] += bf2f(v0.z & 0xffff); acc[5] += bf2f(v0.z >> 16);
            acc[6] += bf2f(v0.w & 0xffff); acc[7] += bf2f(v0.w >> 16);
        }
    } else {
        for (int e = start; e < end; ++e) {
            const float4* vr = reinterpret_cast<const float4*>(x + (size_t)eidx[e] * HID + l * 8);
            float4 v0 = vr[0], v1 = vr[1];
            acc[0] += v0.x; acc[1] += v0.y; acc[2] += v0.z; acc[3] += v0.w;
            acc[4] += v1.x; acc[5] += v1.y; acc[6] += v1.z; acc[7] += v1.w;
        }
    }
    float4* tw = reinterpret_cast<float4*>(t + (size_t)n * HID + l * 8);
    tw[0] = make_float4(acc[0], acc[1], acc[2], acc[3]);
    tw[1] = make_float4(acc[4], acc[5], acc[6], acc[7]);
}

// --------------------------------------------- stat helpers (device)
// mapping A: 64 col-groups x 2 cols (512-thread GEMMs) — LDS atomics
__device__ __forceinline__ void stat_reduce2(float s0, float s1, float q0, float q1,
    int j0, float* ls, float* lq, float* sums)
{
    atomicAdd(&ls[j0], s0);     atomicAdd(&ls[j0 + 1], s1);
    atomicAdd(&lq[j0], q0);     atomicAdd(&lq[j0 + 1], q1);
    __syncthreads();
    if (threadIdx.x < 128) {
        atomicAdd(&sums[threadIdx.x], ls[threadIdx.x]);
        atomicAdd(&sums[128 + threadIdx.x], lq[threadIdx.x]);
    }
}

// mapping B: 32 col-groups x 4 cols (k_app_stat, 256 threads)
__device__ __forceinline__ void stat_reduce4(float* s4, float* q4, int j0,
    float* ls, float* lq, float* sums)
{
    const int lane = threadIdx.x & 63;
    #pragma unroll
    for (int c = 0; c < 4; ++c) {
        s4[c] += __shfl_xor(s4[c], 32);
        q4[c] += __shfl_xor(q4[c], 32);
    }
    if (lane < 32) {
        #pragma unroll
        for (int c = 0; c < 4; ++c) {
            atomicAdd(&ls[j0 + c], s4[c]);
            atomicAdd(&lq[j0 + c], q4[c]);
        }
    }
    __syncthreads();
    if (threadIdx.x < 128) {
        atomicAdd(&sums[threadIdx.x], ls[threadIdx.x]);
        atomicAdd(&sums[128 + threadIdx.x], lq[threadIdx.x]);
    }
}

// --------------------------- GEMM core (Xs staged) : 2 cols x 5 rows / thread
#define GEMM_CORE_1(W, acc)                                                    \
    _Pragma("unroll 8")                                                        \
    for (int k = 0; k < 128; ++k) {                                            \
        const float2 w2 = *reinterpret_cast<const float2*>(W + k * HID + j0);  \
        _Pragma("unroll")                                                      \
        for (int r = 0; r < RPT; ++r) {                                        \
            const float xv = Xs[r0 + r][k];                                    \
            acc[r][0] = fmaf(xv, w2.x, acc[r][0]);                             \
            acc[r][1] = fmaf(xv, w2.y, acc[r][1]);                             \
        }                                                                      \
    }

// plain float4 staging of ROWS x 128 into Xs (512 threads, 1280 chunks)
#define STAGE_PLAIN(X)                                                         \
    _Pragma("unroll")                                                          \
    for (int it = 0; it < 3; ++it) {                                           \
        int f = tid + it * 512;                                                \
        if (f < ROWS * 32) {                                                   \
            int r = f >> 5, kq = (f & 31) << 2;                                \
            *reinterpret_cast<float4*>(&Xs[r][kq]) =                           \
                *reinterpret_cast<const float4*>(X + (size_t)(br + r) * HID + kq);\
        }                                                                      \
    }

// ------------------------------------------------------- GEMM + stat epilogue
// C[N,128] = X@W + bias ; BN partial sums into sums[256]. 40 rows, 512 thr.
__global__ __launch_bounds__(512, 4) void k_gemm_stat(const float* __restrict__ X,
    const float* __restrict__ W, const float* __restrict__ bias,
    float* __restrict__ Cm, float* __restrict__ sums)
{
    __shared__ float Xs[ROWS][XPAD];
    __shared__ float ls[128], lq[128];
    const int tid = threadIdx.x;
    const int br = blockIdx.x * ROWS;
    if (tid < 128) { ls[tid] = 0.f; lq[tid] = 0.f; }
    STAGE_PLAIN(X)
    __syncthreads();
    const int j0 = (tid & 63) * 2;
    const int r0 = (tid >> 6) * RPT;
    float acc[RPT][2];
    #pragma unroll
    for (int r = 0; r < RPT; ++r) { acc[r][0] = 0.f; acc[r][1] = 0.f; }
    GEMM_CORE_1(W, acc)
    const float2 bv = *reinterpret_cast<const float2*>(bias + j0);
    float s0 = 0.f, s1 = 0.f, q0 = 0.f, q1 = 0.f;
    #pragma unroll
    for (int r = 0; r < RPT; ++r) {
        float v0 = acc[r][0] + bv.x, v1 = acc[r][1] + bv.y;
        s0 += v0; s1 += v1;
        q0 = fmaf(v0, v0, q0); q1 = fmaf(v1, v1, q1);
        *reinterpret_cast<float2*>(Cm + (size_t)(br + r0 + r) * HID + j0) =
            make_float2(v0, v1);
    }
    stat_reduce2(s0, s1, q0, q1, j0, ls, lq, sums);
}

// Same, but input transformed by BN(sIn,g,b)+ReLU during LDS staging.
__global__ __launch_bounds__(512, 4) void k_gemm_bnin_stat(const float* __restrict__ X,
    const float* __restrict__ sIn, const float* __restrict__ g, const float* __restrict__ b,
    const float* __restrict__ W, const float* __restrict__ bias,
    float* __restrict__ Cm, float* __restrict__ sums)
{
    __shared__ float Xs[ROWS][XPAD];
    __shared__ float ac[256];
    __shared__ float ls[128], lq[128];
    const int tid = threadIdx.x;
    const int br = blockIdx.x * ROWS;
    if (tid < 128) {
        float m = sIn[tid] * BN_INV;
        float var = fmaf(-m, m, sIn[128 + tid] * BN_INV);
        float a = g[tid] * rsqrtf(var + 1e-5f);
        ac[tid] = a;
        ac[128 + tid] = fmaf(-m, a, b[tid]);
        ls[tid] = 0.f; lq[tid] = 0.f;
    }
    __syncthreads();
    #pragma unroll
    for (int it = 0; it < 3; ++it) {
        int f = tid + it * 512;
        if (f < ROWS * 32) {
            int r = f >> 5, kq = (f & 31) << 2;
            float4 v = *reinterpret_cast<const float4*>(X + (size_t)(br + r) * HID + kq);
            v.x = fmaxf(fmaf(ac[kq + 0], v.x, ac[128 + kq + 0]), 0.f);
            v.y = fmaxf(fmaf(ac[kq + 1], v.y, ac[128 + kq + 1]), 0.f);
            v.z = fmaxf(fmaf(ac[kq + 2], v.z, ac[128 + kq + 2]), 0.f);
            v.w = fmaxf(fmaf(ac[kq + 3], v.w, ac[128 + kq + 3]), 0.f);
            *reinterpret_cast<float4*>(&Xs[r][kq]) = v;
        }
    }
    __syncthreads();
    const int j0 = (tid & 63) * 2;
    const int r0 = (tid >> 6) * RPT;
    float acc[RPT][2];
    #pragma unroll
    for (int r = 0; r < RPT; ++r) { acc[r][0] = 0.f; acc[r][1] = 0.f; }
    GEMM_CORE_1(W, acc)
    const float2 bv = *reinterpret_cast<const float2*>(bias + j0);
    float s0 = 0.f, s1 = 0.f, q0 = 0.f, q1 = 0.f;
    #pragma unroll
    for (int r = 0; r < RPT; ++r) {
        float v0 = acc[r][0] + bv.x, v1 = acc[r][1] + bv.y;
        s0 += v0; s1 += v1;
        q0 = fmaf(v0, v0, q0); q1 = fmaf(v1, v1, q1);
        *reinterpret_cast<float2*>(Cm + (size_t)(br + r0 + r) * HID + j0) =
            make_float2(v0, v1);
    }
    stat_reduce2(s0, s1, q0, q1, j0, ls, lq, sums);
}

// --------------------------------- dual-GEMM body -> bf16 A,B outputs
#define HEAD_GEMM_BODY(W1, b1, A, Bm)                                          \
    const int j0 = (tid & 63) * 2;                                             \
    const int r0 = (tid >> 6) * RPT;                                           \
    float accA[RPT][2], accB[RPT][2];                                          \
    _Pragma("unroll")                                                          \
    for (int r = 0; r < RPT; ++r) {                                            \
        accA[r][0] = 0.f; accA[r][1] = 0.f;                                    \
        accB[r][0] = 0.f; accB[r][1] = 0.f;                                    \
    }                                                                          \
    _Pragma("unroll 4")                                                        \
    for (int k = 0; k < 128; ++k) {                                            \
        const float2 wa = *reinterpret_cast<const float2*>(W1 + k * HID + j0); \
        const float2 wb = *reinterpret_cast<const float2*>(W1 + (HID + k) * HID + j0);\
        _Pragma("unroll")                                                      \
        for (int r = 0; r < RPT; ++r) {                                        \
            const float xv = Xs[r0 + r][k];                                    \
            accA[r][0] = fmaf(xv, wa.x, accA[r][0]);                           \
            accA[r][1] = fmaf(xv, wa.y, accA[r][1]);                           \
            accB[r][0] = fmaf(xv, wb.x, accB[r][0]);                           \
            accB[r][1] = fmaf(xv, wb.y, accB[r][1]);                           \
        }                                                                      \
    }                                                                          \
    const float2 bv1 = *reinterpret_cast<const float2*>(b1 + j0);              \
    _Pragma("unroll")                                                          \
    for (int r = 0; r < RPT; ++r) {                                            \
        size_t rowoff = (size_t)(br + r0 + r) * HID + j0;                      \
        *reinterpret_cast<u32*>(A + rowoff)  = pack2(accA[r][0] + bv1.x,       \
                                                     accA[r][1] + bv1.y);      \
        *reinterpret_cast<u32*>(Bm + rowoff) = pack2(accB[r][0], accB[r][1]);  \
    }

// head 0: plain input staging
__global__ __launch_bounds__(512, 4) void k_gemm_head(const float* __restrict__ X,
    const float* __restrict__ W1, const float* __restrict__ b1,
    u16* __restrict__ A, u16* __restrict__ Bm)
{
    __shared__ float Xs[ROWS][XPAD];
    const int tid = threadIdx.x;
    const int br = blockIdx.x * ROWS;
    STAGE_PLAIN(X)
    __syncthreads();
    HEAD_GEMM_BODY(W1, b1, A, Bm)
}

// heads 1..L: staging computes x += relu(gin(relu(app(v)))), writes x (+xh),
// and uses updated x as the GEMM input.
__global__ __launch_bounds__(512, 4) void k_head_resid(const float* __restrict__ v,
    const float* __restrict__ s1, const float* __restrict__ ga, const float* __restrict__ ba,
    const float* __restrict__ s2, const float* __restrict__ gg, const float* __restrict__ bg,
    float* __restrict__ x, u16* __restrict__ xh,
    const float* __restrict__ W1, const float* __restrict__ b1,
    u16* __restrict__ A, u16* __restrict__ Bm)
{
    __shared__ float Xs[ROWS][XPAD];
    __shared__ float aca[256], acg[256];
    const int tid = threadIdx.x;
    const int br = blockIdx.x * ROWS;
    if (tid < 128) {
        float m = s1[tid] * BN_INV;
        float var = fmaf(-m, m, s1[128 + tid] * BN_INV);
        float a = ga[tid] * rsqrtf(var + 1e-5f);
        aca[tid] = a;
        aca[128 + tid] = fmaf(-m, a, ba[tid]);
        float m2 = s2[tid] * BN_INV;
        float var2 = fmaf(-m2, m2, s2[128 + tid] * BN_INV);
        float a2 = gg[tid] * rsqrtf(var2 + 1e-5f);
        acg[tid] = a2;
        acg[128 + tid] = fmaf(-m2, a2, bg[tid]);
    }
    __syncthreads();
    #pragma unroll
    for (int it = 0; it < 3; ++it) {
        int f = tid + it * 512;
        if (f < ROWS * 32) {
            int r = f >> 5, kq = (f & 31) << 2;
            size_t goff = (size_t)(br + r) * HID + kq;
            float4 vv = *reinterpret_cast<const float4*>(v + goff);
            float4 xv = *reinterpret_cast<const float4*>(x + goff);
            float t0 = fmaxf(fmaf(aca[kq + 0], vv.x, aca[128 + kq + 0]), 0.f);
            float t1 = fmaxf(fmaf(aca[kq + 1], vv.y, aca[128 + kq + 1]), 0.f);
            float t2 = fmaxf(fmaf(aca[kq + 2], vv.z, aca[128 + kq + 2]), 0.f);
            float t3 = fmaxf(fmaf(aca[kq + 3], vv.w, aca[128 + kq + 3]), 0.f);
            xv.x += fmaxf(fmaf(acg[kq + 0], t0, acg[128 + kq + 0]), 0.f);
            xv.y += fmaxf(fmaf(acg[kq + 1], t1, acg[128 + kq + 1]), 0.f);
            xv.z += fmaxf(fmaf(acg[kq + 2], t2, acg[128 + kq + 2]), 0.f);
            xv.w += fmaxf(fmaf(acg[kq + 3], t3, acg[128 + kq + 3]), 0.f);
            *reinterpret_cast<float4*>(x + goff) = xv;
            if (xh) *reinterpret_cast<uint2*>(xh + goff) =
                make_uint2(pack2(xv.x, xv.y), pack2(xv.z, xv.w));
            *reinterpret_cast<float4*>(&Xs[r][kq]) = xv;
        }
    }
    __syncthreads();
    HEAD_GEMM_BODY(W1, b1, A, Bm)
}

// ------------------------------------- stats of relu(app(v)) -> s2
// grid 1250 blocks x 16 rows: thread handles rows row0 and row0+8, 4 cols.
__global__ __launch_bounds__(256) void k_app_stat(const float* __restrict__ v,
    const float* __restrict__ s1, const float* __restrict__ g, const float* __restrict__ b,
    float* __restrict__ s2)
{
    __shared__ float ac[256];
    __shared__ float ls[128], lq[128];
    const int tid = threadIdx.x;
    if (tid < 128) {
        float m = s1[tid] * BN_INV;
        float var = fmaf(-m, m, s1[128 + tid] * BN_INV);
        float a = g[tid] * rsqrtf(var + 1e-5f);
        ac[tid] = a;
        ac[128 + tid] = fmaf(-m, a, b[tid]);
        ls[tid] = 0.f; lq[tid] = 0.f;
    }
    __syncthreads();
    const int j0 = (tid & 31) * 4;
    const int row0 = blockIdx.x * 16 + (tid >> 5);   // rows row0, row0+8
    float s4[4] = {0.f, 0.f, 0.f, 0.f}, q4[4] = {0.f, 0.f, 0.f, 0.f};
    #pragma unroll
    for (int rr = 0; rr < 2; ++rr) {
        const float4 v4 = *reinterpret_cast<const float4*>(
            v + (size_t)(row0 + rr * 8) * HID + j0);
        float w[4] = {v4.x, v4.y, v4.z, v4.w};
        #pragma unroll
        for (int c = 0; c < 4; ++c) {
            w[c] = fmaxf(fmaf(ac[j0 + c], w[c], ac[128 + j0 + c]), 0.f);
            s4[c] += w[c];
            q4[c] = fmaf(w[c], w[c], q4[c]);
        }
    }
    stat_reduce4(s4, q4, j0, ls, lq, s2);
}

// ---------------------------------------------------- edge head (dst-CSR)
// wave = 1 dst node; 16 lanes/edge (uint4 = 8 bf16), 4 edges in flight.
__global__ __launch_bounds__(256) void k_edge_csr(const u16* __restrict__ Ah,
    const u16* __restrict__ Bh, const int* __restrict__ off,
    const u16* __restrict__ eidx, const int* __restrict__ epos,
    const float* __restrict__ w2, const float* __restrict__ b2,
    float* __restrict__ out, int accumulate)
{
    const int wid = (blockIdx.x * 256 + threadIdx.x) >> 6;   // node; grid 5000
    const int lane = threadIdx.x & 63;
    const int q = lane >> 4, l = lane & 15;
    const int start = wid ? off[wid - 1] : 0;
    const int end = off[wid];
    const uint4 bb = *reinterpret_cast<const uint4*>(Bh + (size_t)wid * HID + l * 8);
    float b8[8] = {bf2f(bb.x & 0xffff), bf2f(bb.x >> 16),
                   bf2f(bb.y & 0xffff), bf2f(bb.y >> 16),
                   bf2f(bb.z & 0xffff), bf2f(bb.z >> 16),
                   bf2f(bb.w & 0xffff), bf2f(bb.w >> 16)};
    float w2f[16];
    #pragma unroll
    for (int t = 0; t < 4; ++t)
        *reinterpret_cast<float4*>(&w2f[t * 4]) =
            *reinterpret_cast<const float4*>(w2 + l * 16 + t * 4);
    const float bias0 = b2[0], bias1 = b2[1];
    for (int e = start + q; e < end; e += 4) {
        int s = eidx[e];
        const uint4 aa = *reinterpret_cast<const uint4*>(Ah + (size_t)s * HID + l * 8);
        float a8[8] = {bf2f(aa.x & 0xffff), bf2f(aa.x >> 16),
                       bf2f(aa.y & 0xffff), bf2f(aa.y >> 16),
                       bf2f(aa.z & 0xffff), bf2f(aa.z >> 16),
                       bf2f(aa.w & 0xffff), bf2f(aa.w >> 16)};
        float s0 = 0.f, s1 = 0.f;
        #pragma unroll
        for (int j = 0; j < 8; ++j) {
            float z = fmaxf(a8[j] + b8[j], 0.f);
            s0 = fmaf(z, w2f[j * 2], s0);
            s1 = fmaf(z, w2f[j * 2 + 1], s1);
        }
        #pragma unroll
        for (int m = 8; m >= 1; m >>= 1) {
            s0 += __shfl_xor(s0, m);
            s1 += __shfl_xor(s1, m);
        }
        if (l == 0) {
            int oe = epos[e];
            float o0 = s0 + bias0, o1 = s1 + bias1;
            if (accumulate) {
                out[oe * 2 + 0] += o0;
                out[oe * 2 + 1] += o1;
            } else {
                out[oe * 2 + 0] = o0;
                out[oe * 2 + 1] = o1;
            }
        }
    }
}

// ---------------------------------------------------------------- launch
extern "C" void kernel_launch(void* const* d_in, const int* in_sizes, int n_in,
                              void* d_out, int out_size, void* d_ws, size_t ws_size,
                              hipStream_t stream)
{
    const float* h        = (const float*)d_in[0];
    const int*   src      = (const int*)d_in[1];
    const int*   dst      = (const int*)d_in[2];
    const float* emb_w    = (const float*)d_in[3];
    const float* emb_b    = (const float*)d_in[4];
    const float* eps      = (const float*)d_in[5];
    const float* mlp_w1   = (const float*)d_in[6];
    const float* mlp_b1   = (const float*)d_in[7];
    const float* mlp_bn_g = (const float*)d_in[8];
    const float* mlp_bn_b = (const float*)d_in[9];
    const float* mlp_w2   = (const float*)d_in[10];
    const float* mlp_b2   = (const float*)d_in[11];
    const float* app_bn_g = (const float*)d_in[12];
    const float* app_bn_b = (const float*)d_in[13];
    const float* gin_bn_g = (const float*)d_in[14];
    const float* gin_bn_b = (const float*)d_in[15];
    const float* pred_w1  = (const float*)d_in[16];
    const float* pred_b1  = (const float*)d_in[17];
    const float* pred_w2  = (const float*)d_in[18];
    const float* pred_b2  = (const float*)d_in[19];
    float* out = (float*)d_out;

    float* ws   = (float*)d_ws;
    float* x    = ws;                       // [N,128] f32
    float* tmp1 = ws + NH;                  // [N,128] f32 (v)
    float* tmp2 = ws + 2 * (size_t)NH;      // [N,128] f32 (u), aliased by bf16 A,B
    float* sums = ws + 3 * (size_t)NH;      // [12][256]
    int*   off  = (int*)(sums + 12 * 256);  // [N]
    int*   deg  = off + NNODES;             // [N]
    int*   epos = deg + NNODES;             // [E]
    u16*   eidx = (u16*)(epos + NEDGES);    // [E]
    u16*   ah   = (u16*)tmp2;               // [N,128] bf16 (aliases tmp2 low half)
    u16*   bh   = ah + NH;                  // [N,128] bf16 (aliases tmp2 high half)
    size_t used_bytes = ((size_t)3 * NH + 12 * 256) * 4 + 2ull * NNODES * 4
                        + (size_t)NEDGES * 4 + (size_t)NEDGES * 2;
    u16* xh = (used_bytes + (size_t)NH * 2 <= ws_size) ? (eidx + NEDGES) : nullptr;

    const int NB = NH / 256;                    // 10000
    const int EB = NEDGES / 256;                // 1250
    const int GB = NNODES / ROWS;               // 500
    const int AGB = NNODES * 16 / 256;          // 1250
    const int ASB = NNODES / 16;                // 1250
    const int CEB = NNODES / 4;                 // 5000

    // ---- CSR build (graph static across layers)
    hipMemsetAsync(deg, 0, NNODES * sizeof(int), stream);
    hipMemsetAsync(sums, 0, 12 * 256 * sizeof(float), stream);
    k_hist<<<EB, 256, 0, stream>>>(dst, deg);
    k_scan<<<1, 1024, 0, stream>>>(deg, off);
    k_fill<<<EB, 256, 0, stream>>>(src, dst, off, eidx, epos);

    k_embed<<<NB, 256, 0, stream>>>(h, emb_w, emb_b, x, xh);

    // head 0
    k_gemm_head<<<GB, 512, 0, stream>>>(x, pred_w1, pred_b1, ah, bh);
    k_edge_csr<<<CEB, 256, 0, stream>>>(ah, bh, off, eidx, epos,
                                        pred_w2, pred_b2, out, 0);

    for (int i = 0; i < NL; ++i) {
        float* s0 = sums + (i * 3 + 0) * 256;
        float* s1 = sums + (i * 3 + 1) * 256;
        float* s2 = sums + (i * 3 + 2) * 256;

        // t = (1+eps)*x + sum_in x[src]  (bf16 neighbor reads)
        k_gather<<<AGB, 256, 0, stream>>>(x, xh, off, eidx, eps, i, tmp1);

        // u = t @ W1 + b1 ; stats(u) -> s0
        k_gemm_stat<<<GB, 512, 0, stream>>>(tmp1, mlp_w1 + (size_t)i * HID * HID,
                                            mlp_b1 + i * HID, tmp2, s0);
        // v = relu(BN_s0(u)) @ W2 + b2 ; stats(v) -> s1
        k_gemm_bnin_stat<<<GB, 512, 0, stream>>>(tmp2, s0, mlp_bn_g + i * HID,
                                                 mlp_bn_b + i * HID,
                                                 mlp_w2 + (size_t)i * HID * HID,
                                                 mlp_b2 + i * HID, tmp1, s1);
        // stats(relu(BN_s1(v))) -> s2
        k_app_stat<<<ASB, 256, 0, stream>>>(tmp1, s1, app_bn_g + i * HID,
                                            app_bn_b + i * HID, s2);
        // x += relu(BN_s2(relu(BN_s1(v)))) fused into head GEMM staging;
        // A,B (bf16) overwrite tmp2 (u is dead). Per-block row ownership.
        k_head_resid<<<GB, 512, 0, stream>>>(tmp1, s1, app_bn_g + i * HID,
                                             app_bn_b + i * HID, s2,
                                             gin_bn_g + i * HID, gin_bn_b + i * HID,
                                             x, xh,
                                             pred_w1 + (size_t)(i + 1) * 256 * HID,
                                             pred_b1 + (i + 1) * HID, ah, bh);
        k_edge_csr<<<CEB, 256, 0, stream>>>(ah, bh, off, eidx, epos,
                                            pred_w2 + (i + 1) * HID * 2,
                                            pred_b2 + (i + 1) * 2, out, 1);
    }
}

// Round 10
// 811.342 us; speedup vs baseline: 1.1472x; 1.0350x over previous
//
#include <hip/hip_runtime.h>

#define NNODES 20000
#define NEDGES 320000
#define HID 128
#define NL 4

constexpr int NH = NNODES * HID;
#define BN_INV (1.0f / (float)NNODES)
#define XPAD 132
#define ROWS 40          // rows per GEMM block; 20000/40 = 500 blocks
#define RPT 5            // rows per thread: 8 row-groups * 5
// GEMM thread tile: 5 rows x 4 cols; 32 col-groups (tid&31) x 8 row-groups

typedef unsigned short u16;
typedef unsigned int u32;

// ---------------------------------------------------------------- bf16 utils
__device__ __forceinline__ float bf2f(u32 lo16) {
    union { u32 u; float f; } c; c.u = lo16 << 16; return c.f;
}
__device__ __forceinline__ u16 f2bf(float f) {
    union { float f; u32 u; } c; c.f = f;
    u32 r = c.u + 0x7FFFu + ((c.u >> 16) & 1u);
    return (u16)(r >> 16);
}
__device__ __forceinline__ u32 pack2(float a, float b) {
    return (u32)f2bf(a) | ((u32)f2bf(b) << 16);
}

// ---------------------------------------------------------------- embed
__global__ __launch_bounds__(256) void k_embed(const float* __restrict__ h,
    const float* __restrict__ ew, const float* __restrict__ eb,
    float* __restrict__ x, u16* __restrict__ xh)
{
    int i = blockIdx.x * 256 + threadIdx.x;          // exactly NH threads
    int nrow = i >> 7, j = i & 127;
    float v = fmaf(h[nrow * 2], ew[j], fmaf(h[nrow * 2 + 1], ew[HID + j], eb[j]));
    x[i] = v;
    if (xh) xh[i] = f2bf(v);
}

// ---------------------------------------------------------------- CSR build
__global__ __launch_bounds__(256) void k_hist(const int* __restrict__ dst,
    int* __restrict__ deg)
{
    int e = blockIdx.x * 256 + threadIdx.x;          // exactly NEDGES threads
    atomicAdd(&deg[dst[e]], 1);
}

__global__ __launch_bounds__(1024) void k_scan(const int* __restrict__ deg,
    int* __restrict__ off)
{
    __shared__ int part[1024];
    const int t = threadIdx.x;
    const int lo = t * 20, hi = min(lo + 20, NNODES);
    int s = 0;
    for (int i = lo; i < hi; ++i) s += deg[i];
    part[t] = s;
    __syncthreads();
    for (int d = 1; d < 1024; d <<= 1) {
        int v = (t >= d) ? part[t - d] : 0;
        __syncthreads();
        part[t] += v;
        __syncthreads();
    }
    int base = part[t] - s;                          // exclusive prefix
    for (int i = lo; i < hi; ++i) { off[i] = base; base += deg[i]; }
}

__global__ __launch_bounds__(256) void k_fill(const int* __restrict__ src,
    const int* __restrict__ dst, int* __restrict__ off,
    u16* __restrict__ eidx, int* __restrict__ epos)
{
    int e = blockIdx.x * 256 + threadIdx.x;          // exactly NEDGES threads
    int p = atomicAdd(&off[dst[e]], 1);
    eidx[p] = (u16)src[e];
    epos[p] = e;
}

// --------------------------------------------- stat helpers (device)
// mapping: 32 col-groups x 4 cols; lane^32 pairs same j0, then LDS+global
__device__ __forceinline__ void stat_reduce4(float* s4, float* q4, int j0,
    float* ls, float* lq, float* sums)
{
    const int lane = threadIdx.x & 63;
    #pragma unroll
    for (int c = 0; c < 4; ++c) {
        s4[c] += __shfl_xor(s4[c], 32);
        q4[c] += __shfl_xor(q4[c], 32);
    }
    if (lane < 32) {
        #pragma unroll
        for (int c = 0; c < 4; ++c) {
            atomicAdd(&ls[j0 + c], s4[c]);
            atomicAdd(&lq[j0 + c], q4[c]);
        }
    }
    __syncthreads();
    if (threadIdx.x < 128) {
        atomicAdd(&sums[threadIdx.x], ls[threadIdx.x]);
        atomicAdd(&sums[128 + threadIdx.x], lq[threadIdx.x]);
    }
}

// ------------------------------------------------------- GEMM + stat epilogue
// C[N,128] = X@W + bias ; BN partial sums into sums[256]. 40 rows/block.
__global__ __launch_bounds__(256) void k_gemm_stat(const float* __restrict__ X,
    const float* __restrict__ W, const float* __restrict__ bias,
    float* __restrict__ Cm, float* __restrict__ sums)
{
    __shared__ float Xs[ROWS][XPAD];
    __shared__ float ls[128], lq[128];
    const int tid = threadIdx.x;
    const int br = blockIdx.x * ROWS;
    if (tid < 128) { ls[tid] = 0.f; lq[tid] = 0.f; }
    #pragma unroll
    for (int it = 0; it < 5; ++it) {
        int f = tid + it * 256;
        int r = f >> 5, kq = (f & 31) << 2;
        *reinterpret_cast<float4*>(&Xs[r][kq]) =
            *reinterpret_cast<const float4*>(X + (size_t)(br + r) * HID + kq);
    }
    __syncthreads();
    const int j0 = (tid & 31) * 4;
    const int r0 = (tid >> 5) * RPT;
    float acc[RPT][4];
    #pragma unroll
    for (int r = 0; r < RPT; ++r)
        #pragma unroll
        for (int c = 0; c < 4; ++c) acc[r][c] = 0.f;

    #pragma unroll 4
    for (int k = 0; k < 128; ++k) {
        const float4 w4 = *reinterpret_cast<const float4*>(W + k * HID + j0);
        #pragma unroll
        for (int r = 0; r < RPT; ++r) {
            const float xv = Xs[r0 + r][k];
            acc[r][0] = fmaf(xv, w4.x, acc[r][0]);
            acc[r][1] = fmaf(xv, w4.y, acc[r][1]);
            acc[r][2] = fmaf(xv, w4.z, acc[r][2]);
            acc[r][3] = fmaf(xv, w4.w, acc[r][3]);
        }
    }
    const float4 bv = *reinterpret_cast<const float4*>(bias + j0);
    const float b4[4] = {bv.x, bv.y, bv.z, bv.w};
    float s4[4] = {0.f, 0.f, 0.f, 0.f}, q4[4] = {0.f, 0.f, 0.f, 0.f};
    #pragma unroll
    for (int r = 0; r < RPT; ++r) {
        #pragma unroll
        for (int c = 0; c < 4; ++c) {
            float v = acc[r][c] + b4[c];
            acc[r][c] = v;
            s4[c] += v;
            q4[c] = fmaf(v, v, q4[c]);
        }
        *reinterpret_cast<float4*>(Cm + (size_t)(br + r0 + r) * HID + j0) =
            make_float4(acc[r][0], acc[r][1], acc[r][2], acc[r][3]);
    }
    stat_reduce4(s4, q4, j0, ls, lq, sums);
}

// Same, but input transformed by BN(sIn,g,b)+ReLU during LDS staging.
__global__ __launch_bounds__(256) void k_gemm_bnin_stat(const float* __restrict__ X,
    const float* __restrict__ sIn, const float* __restrict__ g, const float* __restrict__ b,
    const float* __restrict__ W, const float* __restrict__ bias,
    float* __restrict__ Cm, float* __restrict__ sums)
{
    __shared__ float Xs[ROWS][XPAD];
    __shared__ float ac[256];
    __shared__ float ls[128], lq[128];
    const int tid = threadIdx.x;
    const int br = blockIdx.x * ROWS;
    if (tid < 128) {
        float m = sIn[tid] * BN_INV;
        float var = fmaf(-m, m, sIn[128 + tid] * BN_INV);
        float a = g[tid] * rsqrtf(var + 1e-5f);
        ac[tid] = a;
        ac[128 + tid] = fmaf(-m, a, b[tid]);
        ls[tid] = 0.f; lq[tid] = 0.f;
    }
    __syncthreads();
    #pragma unroll
    for (int it = 0; it < 5; ++it) {
        int f = tid + it * 256;
        int r = f >> 5, kq = (f & 31) << 2;
        float4 v = *reinterpret_cast<const float4*>(X + (size_t)(br + r) * HID + kq);
        v.x = fmaxf(fmaf(ac[kq + 0], v.x, ac[128 + kq + 0]), 0.f);
        v.y = fmaxf(fmaf(ac[kq + 1], v.y, ac[128 + kq + 1]), 0.f);
        v.z = fmaxf(fmaf(ac[kq + 2], v.z, ac[128 + kq + 2]), 0.f);
        v.w = fmaxf(fmaf(ac[kq + 3], v.w, ac[128 + kq + 3]), 0.f);
        *reinterpret_cast<float4*>(&Xs[r][kq]) = v;
    }
    __syncthreads();
    const int j0 = (tid & 31) * 4;
    const int r0 = (tid >> 5) * RPT;
    float acc[RPT][4];
    #pragma unroll
    for (int r = 0; r < RPT; ++r)
        #pragma unroll
        for (int c = 0; c < 4; ++c) acc[r][c] = 0.f;

    #pragma unroll 4
    for (int k = 0; k < 128; ++k) {
        const float4 w4 = *reinterpret_cast<const float4*>(W + k * HID + j0);
        #pragma unroll
        for (int r = 0; r < RPT; ++r) {
            const float xv = Xs[r0 + r][k];
            acc[r][0] = fmaf(xv, w4.x, acc[r][0]);
            acc[r][1] = fmaf(xv, w4.y, acc[r][1]);
            acc[r][2] = fmaf(xv, w4.z, acc[r][2]);
            acc[r][3] = fmaf(xv, w4.w, acc[r][3]);
        }
    }
    const float4 bv = *reinterpret_cast<const float4*>(bias + j0);
    const float b4[4] = {bv.x, bv.y, bv.z, bv.w};
    float s4[4] = {0.f, 0.f, 0.f, 0.f}, q4[4] = {0.f, 0.f, 0.f, 0.f};
    #pragma unroll
    for (int r = 0; r < RPT; ++r) {
        #pragma unroll
        for (int c = 0; c < 4; ++c) {
            float v = acc[r][c] + b4[c];
            acc[r][c] = v;
            s4[c] += v;
            q4[c] = fmaf(v, v, q4[c]);
        }
        *reinterpret_cast<float4*>(Cm + (size_t)(br + r0 + r) * HID + j0) =
            make_float4(acc[r][0], acc[r][1], acc[r][2], acc[r][3]);
    }
    stat_reduce4(s4, q4, j0, ls, lq, sums);
}

// --------------------------------- dual-GEMM body -> bf16 A,B outputs
#define HEAD_GEMM_BODY(W1, b1, A, Bm)                                          \
    const int j0 = (tid & 31) * 4;                                             \
    const int r0 = (tid >> 5) * RPT;                                           \
    float accA[RPT][4], accB[RPT][4];                                          \
    _Pragma("unroll")                                                          \
    for (int r = 0; r < RPT; ++r) {                                            \
        _Pragma("unroll")                                                      \
        for (int c = 0; c < 4; ++c) { accA[r][c] = 0.f; accB[r][c] = 0.f; }    \
    }                                                                          \
    _Pragma("unroll 4")                                                        \
    for (int k = 0; k < 128; ++k) {                                            \
        const float4 wa = *reinterpret_cast<const float4*>(W1 + k * HID + j0); \
        const float4 wb = *reinterpret_cast<const float4*>(W1 + (HID + k) * HID + j0);\
        _Pragma("unroll")                                                      \
        for (int r = 0; r < RPT; ++r) {                                        \
            const float xv = Xs[r0 + r][k];                                    \
            accA[r][0] = fmaf(xv, wa.x, accA[r][0]);                           \
            accA[r][1] = fmaf(xv, wa.y, accA[r][1]);                           \
            accA[r][2] = fmaf(xv, wa.z, accA[r][2]);                           \
            accA[r][3] = fmaf(xv, wa.w, accA[r][3]);                           \
            accB[r][0] = fmaf(xv, wb.x, accB[r][0]);                           \
            accB[r][1] = fmaf(xv, wb.y, accB[r][1]);                           \
            accB[r][2] = fmaf(xv, wb.z, accB[r][2]);                           \
            accB[r][3] = fmaf(xv, wb.w, accB[r][3]);                           \
        }                                                                      \
    }                                                                          \
    const float4 bv1 = *reinterpret_cast<const float4*>(b1 + j0);              \
    _Pragma("unroll")                                                          \
    for (int r = 0; r < RPT; ++r) {                                            \
        size_t rowoff = (size_t)(br + r0 + r) * HID + j0;                      \
        uint2 av, bvv;                                                         \
        av.x = pack2(accA[r][0] + bv1.x, accA[r][1] + bv1.y);                  \
        av.y = pack2(accA[r][2] + bv1.z, accA[r][3] + bv1.w);                  \
        bvv.x = pack2(accB[r][0], accB[r][1]);                                 \
        bvv.y = pack2(accB[r][2], accB[r][3]);                                 \
        *reinterpret_cast<uint2*>(A + rowoff)  = av;                           \
        *reinterpret_cast<uint2*>(Bm + rowoff) = bvv;                          \
    }

// head 0: plain input staging
__global__ __launch_bounds__(256) void k_gemm_head(const float* __restrict__ X,
    const float* __restrict__ W1, const float* __restrict__ b1,
    u16* __restrict__ A, u16* __restrict__ Bm)
{
    __shared__ float Xs[ROWS][XPAD];
    const int tid = threadIdx.x;
    const int br = blockIdx.x * ROWS;
    #pragma unroll
    for (int it = 0; it < 5; ++it) {
        int f = tid + it * 256;
        int r = f >> 5, kq = (f & 31) << 2;
        *reinterpret_cast<float4*>(&Xs[r][kq]) =
            *reinterpret_cast<const float4*>(X + (size_t)(br + r) * HID + kq);
    }
    __syncthreads();
    HEAD_GEMM_BODY(W1, b1, A, Bm)
}

// heads 1..L: staging computes x += relu(gin(relu(app(v)))), writes x (+xh),
// and uses updated x as the GEMM input.
__global__ __launch_bounds__(256) void k_head_resid(const float* __restrict__ v,
    const float* __restrict__ s1, const float* __restrict__ ga, const float* __restrict__ ba,
    const float* __restrict__ s2, const float* __restrict__ gg, const float* __restrict__ bg,
    float* __restrict__ x, u16* __restrict__ xh,
    const float* __restrict__ W1, const float* __restrict__ b1,
    u16* __restrict__ A, u16* __restrict__ Bm)
{
    __shared__ float Xs[ROWS][XPAD];
    __shared__ float aca[256], acg[256];
    const int tid = threadIdx.x;
    const int br = blockIdx.x * ROWS;
    if (tid < 128) {
        float m = s1[tid] * BN_INV;
        float var = fmaf(-m, m, s1[128 + tid] * BN_INV);
        float a = ga[tid] * rsqrtf(var + 1e-5f);
        aca[tid] = a;
        aca[128 + tid] = fmaf(-m, a, ba[tid]);
        float m2 = s2[tid] * BN_INV;
        float var2 = fmaf(-m2, m2, s2[128 + tid] * BN_INV);
        float a2 = gg[tid] * rsqrtf(var2 + 1e-5f);
        acg[tid] = a2;
        acg[128 + tid] = fmaf(-m2, a2, bg[tid]);
    }
    __syncthreads();
    #pragma unroll
    for (int it = 0; it < 5; ++it) {
        int f = tid + it * 256;
        int r = f >> 5, kq = (f & 31) << 2;
        size_t goff = (size_t)(br + r) * HID + kq;
        float4 vv = *reinterpret_cast<const float4*>(v + goff);
        float4 xv = *reinterpret_cast<const float4*>(x + goff);
        float t0 = fmaxf(fmaf(aca[kq + 0], vv.x, aca[128 + kq + 0]), 0.f);
        float t1 = fmaxf(fmaf(aca[kq + 1], vv.y, aca[128 + kq + 1]), 0.f);
        float t2 = fmaxf(fmaf(aca[kq + 2], vv.z, aca[128 + kq + 2]), 0.f);
        float t3 = fmaxf(fmaf(aca[kq + 3], vv.w, aca[128 + kq + 3]), 0.f);
        xv.x += fmaxf(fmaf(acg[kq + 0], t0, acg[128 + kq + 0]), 0.f);
        xv.y += fmaxf(fmaf(acg[kq + 1], t1, acg[128 + kq + 1]), 0.f);
        xv.z += fmaxf(fmaf(acg[kq + 2], t2, acg[128 + kq + 2]), 0.f);
        xv.w += fmaxf(fmaf(acg[kq + 3], t3, acg[128 + kq + 3]), 0.f);
        *reinterpret_cast<float4*>(x + goff) = xv;
        if (xh) *reinterpret_cast<uint2*>(xh + goff) =
            make_uint2(pack2(xv.x, xv.y), pack2(xv.z, xv.w));
        *reinterpret_cast<float4*>(&Xs[r][kq]) = xv;
    }
    __syncthreads();
    HEAD_GEMM_BODY(W1, b1, A, Bm)
}

// ------------------------------------- stats of relu(app(v)) -> s2
// grid 1250 blocks x 16 rows: thread handles rows row0 and row0+8, 4 cols.
__global__ __launch_bounds__(256) void k_app_stat(const float* __restrict__ v,
    const float* __restrict__ s1, const float* __restrict__ g, const float* __restrict__ b,
    float* __restrict__ s2)
{
    __shared__ float ac[256];
    __shared__ float ls[128], lq[128];
    const int tid = threadIdx.x;
    if (tid < 128) {
        float m = s1[tid] * BN_INV;
        float var = fmaf(-m, m, s1[128 + tid] * BN_INV);
        float a = g[tid] * rsqrtf(var + 1e-5f);
        ac[tid] = a;
        ac[128 + tid] = fmaf(-m, a, b[tid]);
        ls[tid] = 0.f; lq[tid] = 0.f;
    }
    __syncthreads();
    const int j0 = (tid & 31) * 4;
    const int row0 = blockIdx.x * 16 + (tid >> 5);   // rows row0, row0+8
    float s4[4] = {0.f, 0.f, 0.f, 0.f}, q4[4] = {0.f, 0.f, 0.f, 0.f};
    #pragma unroll
    for (int rr = 0; rr < 2; ++rr) {
        const float4 v4 = *reinterpret_cast<const float4*>(
            v + (size_t)(row0 + rr * 8) * HID + j0);
        float w[4] = {v4.x, v4.y, v4.z, v4.w};
        #pragma unroll
        for (int c = 0; c < 4; ++c) {
            w[c] = fmaxf(fmaf(ac[j0 + c], w[c], ac[128 + j0 + c]), 0.f);
            s4[c] += w[c];
            q4[c] = fmaf(w[c], w[c], q4[c]);
        }
    }
    stat_reduce4(s4, q4, j0, ls, lq, s2);
}

// ---------------------------------------------------- edge head (dst-CSR)
// wave = 1 dst node; 16 lanes/edge, 4 edges/wave. Used for the LAST head only.
__global__ __launch_bounds__(256) void k_edge_csr(const u16* __restrict__ Ah,
    const u16* __restrict__ Bh, const int* __restrict__ off,
    const u16* __restrict__ eidx, const int* __restrict__ epos,
    const float* __restrict__ w2, const float* __restrict__ b2,
    float* __restrict__ out, int accumulate)
{
    const int wid = (blockIdx.x * 256 + threadIdx.x) >> 6;   // node; grid 5000
    const int lane = threadIdx.x & 63;
    const int q = lane >> 4, l = lane & 15;
    const int start = wid ? off[wid - 1] : 0;
    const int end = off[wid];
    const uint4 bb = *reinterpret_cast<const uint4*>(Bh + (size_t)wid * HID + l * 8);
    float b8[8] = {bf2f(bb.x & 0xffff), bf2f(bb.x >> 16),
                   bf2f(bb.y & 0xffff), bf2f(bb.y >> 16),
                   bf2f(bb.z & 0xffff), bf2f(bb.z >> 16),
                   bf2f(bb.w & 0xffff), bf2f(bb.w >> 16)};
    float w2f[16];
    #pragma unroll
    for (int t = 0; t < 4; ++t)
        *reinterpret_cast<float4*>(&w2f[t * 4]) =
            *reinterpret_cast<const float4*>(w2 + l * 16 + t * 4);
    const float bias0 = b2[0], bias1 = b2[1];
    for (int e = start + q; e < end; e += 4) {
        int s = eidx[e];
        const uint4 aa = *reinterpret_cast<const uint4*>(Ah + (size_t)s * HID + l * 8);
        float a8[8] = {bf2f(aa.x & 0xffff), bf2f(aa.x >> 16),
                       bf2f(aa.y & 0xffff), bf2f(aa.y >> 16),
                       bf2f(aa.z & 0xffff), bf2f(aa.z >> 16),
                       bf2f(aa.w & 0xffff), bf2f(aa.w >> 16)};
        float s0 = 0.f, s1 = 0.f;
        #pragma unroll
        for (int j = 0; j < 8; ++j) {
            float z = fmaxf(a8[j] + b8[j], 0.f);
            s0 = fmaf(z, w2f[j * 2], s0);
            s1 = fmaf(z, w2f[j * 2 + 1], s1);
        }
        #pragma unroll
        for (int m = 8; m >= 1; m >>= 1) {
            s0 += __shfl_xor(s0, m);
            s1 += __shfl_xor(s1, m);
        }
        if (l == 0) {
            int oe = epos[e];
            float o0 = s0 + bias0, o1 = s1 + bias1;
            if (accumulate) {
                out[oe * 2 + 0] += o0;
                out[oe * 2 + 1] += o1;
            } else {
                out[oe * 2 + 0] = o0;
                out[oe * 2 + 1] = o1;
            }
        }
    }
}

// ------------------------- merged edge head + gather (one CSR pass)
// Per dst node: edge scores for head i AND t[n] = (1+eps)*x[n] + sum xh[src].
// Each 16-lane group walks edges stride-4 issuing A[s]+xh[s] loads together.
__global__ __launch_bounds__(256) void k_edge_gather(const u16* __restrict__ Ah,
    const u16* __restrict__ Bh, const float* __restrict__ x,
    const u16* __restrict__ xh, const int* __restrict__ off,
    const u16* __restrict__ eidx, const int* __restrict__ epos,
    const float* __restrict__ w2, const float* __restrict__ b2,
    float* __restrict__ out, int accumulate,
    const float* __restrict__ eps, int layer, float* __restrict__ t)
{
    const int wid = (blockIdx.x * 256 + threadIdx.x) >> 6;   // node; grid 5000
    const int lane = threadIdx.x & 63;
    const int q = lane >> 4, l = lane & 15;
    const int start = wid ? off[wid - 1] : 0;
    const int end = off[wid];
    const uint4 bb = *reinterpret_cast<const uint4*>(Bh + (size_t)wid * HID + l * 8);
    float b8[8] = {bf2f(bb.x & 0xffff), bf2f(bb.x >> 16),
                   bf2f(bb.y & 0xffff), bf2f(bb.y >> 16),
                   bf2f(bb.z & 0xffff), bf2f(bb.z >> 16),
                   bf2f(bb.w & 0xffff), bf2f(bb.w >> 16)};
    float w2f[16];
    #pragma unroll
    for (int tt = 0; tt < 4; ++tt)
        *reinterpret_cast<float4*>(&w2f[tt * 4]) =
            *reinterpret_cast<const float4*>(w2 + l * 16 + tt * 4);
    const float bias0 = b2[0], bias1 = b2[1];
    float g8[8] = {0.f, 0.f, 0.f, 0.f, 0.f, 0.f, 0.f, 0.f};

    #define EG_BODY(EE)                                                        \
    {                                                                          \
        int s = eidx[EE];                                                      \
        const uint4 aa = *reinterpret_cast<const uint4*>(Ah + (size_t)s * HID + l * 8);\
        const uint4 gv = *reinterpret_cast<const uint4*>(xh + (size_t)s * HID + l * 8);\
        g8[0] += bf2f(gv.x & 0xffff); g8[1] += bf2f(gv.x >> 16);               \
        g8[2] += bf2f(gv.y & 0xffff); g8[3] += bf2f(gv.y >> 16);               \
        g8[4] += bf2f(gv.z & 0xffff); g8[5] += bf2f(gv.z >> 16);               \
        g8[6] += bf2f(gv.w & 0xffff); g8[7] += bf2f(gv.w >> 16);               \
        float a8[8] = {bf2f(aa.x & 0xffff), bf2f(aa.x >> 16),                  \
                       bf2f(aa.y & 0xffff), bf2f(aa.y >> 16),                  \
                       bf2f(aa.z & 0xffff), bf2f(aa.z >> 16),                  \
                       bf2f(aa.w & 0xffff), bf2f(aa.w >> 16)};                 \
        float s0 = 0.f, s1 = 0.f;                                              \
        _Pragma("unroll")                                                      \
        for (int j = 0; j < 8; ++j) {                                          \
            float z = fmaxf(a8[j] + b8[j], 0.f);                               \
            s0 = fmaf(z, w2f[j * 2], s0);                                      \
            s1 = fmaf(z, w2f[j * 2 + 1], s1);                                  \
        }                                                                      \
        _Pragma("unroll")                                                      \
        for (int m = 8; m >= 1; m >>= 1) {                                     \
            s0 += __shfl_xor(s0, m);                                           \
            s1 += __shfl_xor(s1, m);                                           \
        }                                                                      \
        if (l == 0) {                                                          \
            int oe = epos[EE];                                                 \
            float o0 = s0 + bias0, o1 = s1 + bias1;                            \
            if (accumulate) { out[oe * 2] += o0; out[oe * 2 + 1] += o1; }      \
            else            { out[oe * 2]  = o0; out[oe * 2 + 1]  = o1; }      \
        }                                                                      \
    }

    int e = start + q;
    for (; e + 4 < end; e += 8) {      // 2 edges in flight per group
        EG_BODY(e)
        EG_BODY(e + 4)
    }
    if (e < end) EG_BODY(e)
    #undef EG_BODY

    // combine the 4 groups' gather partials: lanes {l, l+16, l+32, l+48}
    #pragma unroll
    for (int j = 0; j < 8; ++j) {
        g8[j] += __shfl_xor(g8[j], 16);
        g8[j] += __shfl_xor(g8[j], 32);
    }
    if (q == 0) {
        const float e1 = 1.0f + eps[layer];
        const float4* xr = reinterpret_cast<const float4*>(x + (size_t)wid * HID + l * 8);
        float4 a0 = xr[0], a1 = xr[1];
        float4* tw = reinterpret_cast<float4*>(t + (size_t)wid * HID + l * 8);
        tw[0] = make_float4(fmaf(a0.x, e1, g8[0]), fmaf(a0.y, e1, g8[1]),
                            fmaf(a0.z, e1, g8[2]), fmaf(a0.w, e1, g8[3]));
        tw[1] = make_float4(fmaf(a1.x, e1, g8[4]), fmaf(a1.y, e1, g8[5]),
                            fmaf(a1.z, e1, g8[6]), fmaf(a1.w, e1, g8[7]));
    }
}

// ---------------------------------------------------------------- launch
extern "C" void kernel_launch(void* const* d_in, const int* in_sizes, int n_in,
                              void* d_out, int out_size, void* d_ws, size_t ws_size,
                              hipStream_t stream)
{
    const float* h        = (const float*)d_in[0];
    const int*   src      = (const int*)d_in[1];
    const int*   dst      = (const int*)d_in[2];
    const float* emb_w    = (const float*)d_in[3];
    const float* emb_b    = (const float*)d_in[4];
    const float* eps      = (const float*)d_in[5];
    const float* mlp_w1   = (const float*)d_in[6];
    const float* mlp_b1   = (const float*)d_in[7];
    const float* mlp_bn_g = (const float*)d_in[8];
    const float* mlp_bn_b = (const float*)d_in[9];
    const float* mlp_w2   = (const float*)d_in[10];
    const float* mlp_b2   = (const float*)d_in[11];
    const float* app_bn_g = (const float*)d_in[12];
    const float* app_bn_b = (const float*)d_in[13];
    const float* gin_bn_g = (const float*)d_in[14];
    const float* gin_bn_b = (const float*)d_in[15];
    const float* pred_w1  = (const float*)d_in[16];
    const float* pred_b1  = (const float*)d_in[17];
    const float* pred_w2  = (const float*)d_in[18];
    const float* pred_b2  = (const float*)d_in[19];
    float* out = (float*)d_out;

    float* ws   = (float*)d_ws;
    float* x    = ws;                       // [N,128] f32
    float* tmp1 = ws + NH;                  // [N,128] f32 (t / v)
    float* tmp2 = ws + 2 * (size_t)NH;      // [N,128] f32 (u), aliased by bf16 A,B
    float* sums = ws + 3 * (size_t)NH;      // [12][256]
    int*   off  = (int*)(sums + 12 * 256);  // [N]
    int*   deg  = off + NNODES;             // [N]
    int*   epos = deg + NNODES;             // [E]
    u16*   eidx = (u16*)(epos + NEDGES);    // [E]
    u16*   ah   = (u16*)tmp2;               // [N,128] bf16 (aliases tmp2 low half)
    u16*   bh   = ah + NH;                  // [N,128] bf16 (aliases tmp2 high half)
    size_t used_bytes = ((size_t)3 * NH + 12 * 256) * 4 + 2ull * NNODES * 4
                        + (size_t)NEDGES * 4 + (size_t)NEDGES * 2;
    u16* xh = (used_bytes + (size_t)NH * 2 <= ws_size) ? (eidx + NEDGES) : nullptr;
    // NOTE: k_edge_gather requires xh; assert-equivalent fallback below keeps
    // the old split path if the workspace were ever too small.

    const int NB = NH / 256;                    // 10000
    const int EB = NEDGES / 256;                // 1250
    const int GB = NNODES / ROWS;               // 500
    const int ASB = NNODES / 16;                // 1250
    const int CEB = NNODES / 4;                 // 5000

    // ---- CSR build (graph static across layers)
    hipMemsetAsync(deg, 0, NNODES * sizeof(int), stream);
    hipMemsetAsync(sums, 0, 12 * 256 * sizeof(float), stream);
    k_hist<<<EB, 256, 0, stream>>>(dst, deg);
    k_scan<<<1, 1024, 0, stream>>>(deg, off);
    k_fill<<<EB, 256, 0, stream>>>(src, dst, off, eidx, epos);

    k_embed<<<NB, 256, 0, stream>>>(h, emb_w, emb_b, x, xh);

    // head 0 GEMM
    k_gemm_head<<<GB, 256, 0, stream>>>(x, pred_w1, pred_b1, ah, bh);

    for (int i = 0; i < NL; ++i) {
        float* s0 = sums + (i * 3 + 0) * 256;
        float* s1 = sums + (i * 3 + 1) * 256;
        float* s2 = sums + (i * 3 + 2) * 256;

        // merged: edge scores for head i  +  t = (1+eps)x + sum xh[src]
        k_edge_gather<<<CEB, 256, 0, stream>>>(ah, bh, x, xh, off, eidx, epos,
                                               pred_w2 + i * HID * 2,
                                               pred_b2 + i * 2, out, (i > 0),
                                               eps, i, tmp1);

        // u = t @ W1 + b1 ; stats(u) -> s0
        k_gemm_stat<<<GB, 256, 0, stream>>>(tmp1, mlp_w1 + (size_t)i * HID * HID,
                                            mlp_b1 + i * HID, tmp2, s0);
        // v = relu(BN_s0(u)) @ W2 + b2 ; stats(v) -> s1
        k_gemm_bnin_stat<<<GB, 256, 0, stream>>>(tmp2, s0, mlp_bn_g + i * HID,
                                                 mlp_bn_b + i * HID,
                                                 mlp_w2 + (size_t)i * HID * HID,
                                                 mlp_b2 + i * HID, tmp1, s1);
        // stats(relu(BN_s1(v))) -> s2
        k_app_stat<<<ASB, 256, 0, stream>>>(tmp1, s1, app_bn_g + i * HID,
                                            app_bn_b + i * HID, s2);
        // x += relu(BN_s2(relu(BN_s1(v)))) fused into head GEMM staging;
        // A,B (bf16) overwrite tmp2 (u is dead). Per-block row ownership.
        k_head_resid<<<GB, 256, 0, stream>>>(tmp1, s1, app_bn_g + i * HID,
                                             app_bn_b + i * HID, s2,
                                             gin_bn_g + i * HID, gin_bn_b + i * HID,
                                             x, xh,
                                             pred_w1 + (size_t)(i + 1) * 256 * HID,
                                             pred_b1 + (i + 1) * HID, ah, bh);
    }
    // last head's edge scores (no following gather)
    k_edge_csr<<<CEB, 256, 0, stream>>>(ah, bh, off, eidx, epos,
                                        pred_w2 + NL * HID * 2,
                                        pred_b2 + NL * 2, out, 1);
}

// Round 11
// 763.042 us; speedup vs baseline: 1.2198x; 1.0633x over previous
//
#include <hip/hip_runtime.h>

#define NNODES 20000
#define NEDGES 320000
#define HID 128
#define NL 4

constexpr int NH = NNODES * HID;
#define BN_INV (1.0f / (float)NNODES)
#define XPAD 132
#define ROWS 40          // MLP GEMM rows/block; 500 blocks
#define RPT 5
#define HROWS 32         // head MFMA GEMM rows/block; 625 blocks

typedef unsigned short u16;
typedef unsigned int u32;
typedef __attribute__((ext_vector_type(8))) short bf16x8;
typedef __attribute__((ext_vector_type(4))) float f32x4;

// ---------------------------------------------------------------- bf16 utils
__device__ __forceinline__ float bf2f(u32 lo16) {
    union { u32 u; float f; } c; c.u = lo16 << 16; return c.f;
}
__device__ __forceinline__ u16 f2bf(float f) {
    union { float f; u32 u; } c; c.f = f;
    u32 r = c.u + 0x7FFFu + ((c.u >> 16) & 1u);
    return (u16)(r >> 16);
}
__device__ __forceinline__ u32 pack2(float a, float b) {
    return (u32)f2bf(a) | ((u32)f2bf(b) << 16);
}

// ---------------------------------------------------------------- embed
__global__ __launch_bounds__(256) void k_embed(const float* __restrict__ h,
    const float* __restrict__ ew, const float* __restrict__ eb,
    float* __restrict__ x, u16* __restrict__ xh)
{
    int i = blockIdx.x * 256 + threadIdx.x;          // exactly NH threads
    int nrow = i >> 7, j = i & 127;
    float v = fmaf(h[nrow * 2], ew[j], fmaf(h[nrow * 2 + 1], ew[HID + j], eb[j]));
    x[i] = v;
    xh[i] = f2bf(v);
}

// ------------------------------------------ one-time bf16 weight transpose
// wt[h][s][c][k] = pred_w1[h][s*128+k][c]; 5*2*128*128 = 163840 elements
__global__ __launch_bounds__(256) void k_wt(const float* __restrict__ pw1,
    u16* __restrict__ wt)
{
    int i = blockIdx.x * 256 + threadIdx.x;          // 640 blocks
    int k = i & 127;
    int c = (i >> 7) & 127;
    int sh = i >> 14;                                // h*2+s
    wt[i] = f2bf(pw1[(size_t)(sh >> 1) * 256 * 128 + (((sh & 1) * 128 + k) << 7) + c]);
}

// ---------------------------------------------------------------- CSR build
__global__ __launch_bounds__(256) void k_hist(const int* __restrict__ dst,
    int* __restrict__ deg)
{
    int e = blockIdx.x * 256 + threadIdx.x;
    atomicAdd(&deg[dst[e]], 1);
}

__global__ __launch_bounds__(1024) void k_scan(const int* __restrict__ deg,
    int* __restrict__ off)
{
    __shared__ int part[1024];
    const int t = threadIdx.x;
    const int lo = t * 20, hi = min(lo + 20, NNODES);
    int s = 0;
    for (int i = lo; i < hi; ++i) s += deg[i];
    part[t] = s;
    __syncthreads();
    for (int d = 1; d < 1024; d <<= 1) {
        int v = (t >= d) ? part[t - d] : 0;
        __syncthreads();
        part[t] += v;
        __syncthreads();
    }
    int base = part[t] - s;
    for (int i = lo; i < hi; ++i) { off[i] = base; base += deg[i]; }
}

__global__ __launch_bounds__(256) void k_fill(const int* __restrict__ src,
    const int* __restrict__ dst, int* __restrict__ off,
    u16* __restrict__ eidx, int* __restrict__ epos)
{
    int e = blockIdx.x * 256 + threadIdx.x;
    int p = atomicAdd(&off[dst[e]], 1);
    eidx[p] = (u16)src[e];
    epos[p] = e;
}

// --------------------------------------------- stat helpers (device)
__device__ __forceinline__ void stat_reduce4(float* s4, float* q4, int j0,
    float* ls, float* lq, float* sums)
{
    const int lane = threadIdx.x & 63;
    #pragma unroll
    for (int c = 0; c < 4; ++c) {
        s4[c] += __shfl_xor(s4[c], 32);
        q4[c] += __shfl_xor(q4[c], 32);
    }
    if (lane < 32) {
        #pragma unroll
        for (int c = 0; c < 4; ++c) {
            atomicAdd(&ls[j0 + c], s4[c]);
            atomicAdd(&lq[j0 + c], q4[c]);
        }
    }
    __syncthreads();
    if (threadIdx.x < 128) {
        atomicAdd(&sums[threadIdx.x], ls[threadIdx.x]);
        atomicAdd(&sums[128 + threadIdx.x], lq[threadIdx.x]);
    }
}

// ------------------------------------------------------- MLP GEMM + stats
__global__ __launch_bounds__(256) void k_gemm_stat(const float* __restrict__ X,
    const float* __restrict__ W, const float* __restrict__ bias,
    float* __restrict__ Cm, float* __restrict__ sums)
{
    __shared__ float Xs[ROWS][XPAD];
    __shared__ float ls[128], lq[128];
    const int tid = threadIdx.x;
    const int br = blockIdx.x * ROWS;
    if (tid < 128) { ls[tid] = 0.f; lq[tid] = 0.f; }
    #pragma unroll
    for (int it = 0; it < 5; ++it) {
        int f = tid + it * 256;
        int r = f >> 5, kq = (f & 31) << 2;
        *reinterpret_cast<float4*>(&Xs[r][kq]) =
            *reinterpret_cast<const float4*>(X + (size_t)(br + r) * HID + kq);
    }
    __syncthreads();
    const int j0 = (tid & 31) * 4;
    const int r0 = (tid >> 5) * RPT;
    float acc[RPT][4];
    #pragma unroll
    for (int r = 0; r < RPT; ++r)
        #pragma unroll
        for (int c = 0; c < 4; ++c) acc[r][c] = 0.f;

    #pragma unroll 4
    for (int k = 0; k < 128; ++k) {
        const float4 w4 = *reinterpret_cast<const float4*>(W + k * HID + j0);
        #pragma unroll
        for (int r = 0; r < RPT; ++r) {
            const float xv = Xs[r0 + r][k];
            acc[r][0] = fmaf(xv, w4.x, acc[r][0]);
            acc[r][1] = fmaf(xv, w4.y, acc[r][1]);
            acc[r][2] = fmaf(xv, w4.z, acc[r][2]);
            acc[r][3] = fmaf(xv, w4.w, acc[r][3]);
        }
    }
    const float4 bv = *reinterpret_cast<const float4*>(bias + j0);
    const float b4[4] = {bv.x, bv.y, bv.z, bv.w};
    float s4[4] = {0.f, 0.f, 0.f, 0.f}, q4[4] = {0.f, 0.f, 0.f, 0.f};
    #pragma unroll
    for (int r = 0; r < RPT; ++r) {
        #pragma unroll
        for (int c = 0; c < 4; ++c) {
            float v = acc[r][c] + b4[c];
            acc[r][c] = v;
            s4[c] += v;
            q4[c] = fmaf(v, v, q4[c]);
        }
        *reinterpret_cast<float4*>(Cm + (size_t)(br + r0 + r) * HID + j0) =
            make_float4(acc[r][0], acc[r][1], acc[r][2], acc[r][3]);
    }
    stat_reduce4(s4, q4, j0, ls, lq, sums);
}

__global__ __launch_bounds__(256) void k_gemm_bnin_stat(const float* __restrict__ X,
    const float* __restrict__ sIn, const float* __restrict__ g, const float* __restrict__ b,
    const float* __restrict__ W, const float* __restrict__ bias,
    float* __restrict__ Cm, float* __restrict__ sums)
{
    __shared__ float Xs[ROWS][XPAD];
    __shared__ float ac[256];
    __shared__ float ls[128], lq[128];
    const int tid = threadIdx.x;
    const int br = blockIdx.x * ROWS;
    if (tid < 128) {
        float m = sIn[tid] * BN_INV;
        float var = fmaf(-m, m, sIn[128 + tid] * BN_INV);
        float a = g[tid] * rsqrtf(var + 1e-5f);
        ac[tid] = a;
        ac[128 + tid] = fmaf(-m, a, b[tid]);
        ls[tid] = 0.f; lq[tid] = 0.f;
    }
    __syncthreads();
    #pragma unroll
    for (int it = 0; it < 5; ++it) {
        int f = tid + it * 256;
        int r = f >> 5, kq = (f & 31) << 2;
        float4 v = *reinterpret_cast<const float4*>(X + (size_t)(br + r) * HID + kq);
        v.x = fmaxf(fmaf(ac[kq + 0], v.x, ac[128 + kq + 0]), 0.f);
        v.y = fmaxf(fmaf(ac[kq + 1], v.y, ac[128 + kq + 1]), 0.f);
        v.z = fmaxf(fmaf(ac[kq + 2], v.z, ac[128 + kq + 2]), 0.f);
        v.w = fmaxf(fmaf(ac[kq + 3], v.w, ac[128 + kq + 3]), 0.f);
        *reinterpret_cast<float4*>(&Xs[r][kq]) = v;
    }
    __syncthreads();
    const int j0 = (tid & 31) * 4;
    const int r0 = (tid >> 5) * RPT;
    float acc[RPT][4];
    #pragma unroll
    for (int r = 0; r < RPT; ++r)
        #pragma unroll
        for (int c = 0; c < 4; ++c) acc[r][c] = 0.f;

    #pragma unroll 4
    for (int k = 0; k < 128; ++k) {
        const float4 w4 = *reinterpret_cast<const float4*>(W + k * HID + j0);
        #pragma unroll
        for (int r = 0; r < RPT; ++r) {
            const float xv = Xs[r0 + r][k];
            acc[r][0] = fmaf(xv, w4.x, acc[r][0]);
            acc[r][1] = fmaf(xv, w4.y, acc[r][1]);
            acc[r][2] = fmaf(xv, w4.z, acc[r][2]);
            acc[r][3] = fmaf(xv, w4.w, acc[r][3]);
        }
    }
    const float4 bv = *reinterpret_cast<const float4*>(bias + j0);
    const float b4[4] = {bv.x, bv.y, bv.z, bv.w};
    float s4[4] = {0.f, 0.f, 0.f, 0.f}, q4[4] = {0.f, 0.f, 0.f, 0.f};
    #pragma unroll
    for (int r = 0; r < RPT; ++r) {
        #pragma unroll
        for (int c = 0; c < 4; ++c) {
            float v = acc[r][c] + b4[c];
            acc[r][c] = v;
            s4[c] += v;
            q4[c] = fmaf(v, v, q4[c]);
        }
        *reinterpret_cast<float4*>(Cm + (size_t)(br + r0 + r) * HID + j0) =
            make_float4(acc[r][0], acc[r][1], acc[r][2], acc[r][3]);
    }
    stat_reduce4(s4, q4, j0, ls, lq, sums);
}

// ---------------------------------------------- MFMA head GEMM core (shared)
// Xs: bf16 [HROWS][136]; Wt: [2][128][128] bf16 (A then B, col-major in k)
// 4 waves: wave w -> row-tile (w>>1), col-quad (w&1). Out via padded LDS.
#define HEAD_MFMA_BODY(wtbase, b1, A, Bm)                                      \
    {                                                                          \
    const int w = tid >> 6;                                                    \
    const int lane = tid & 63;                                                 \
    const int rt = w >> 1;                                                     \
    const int cg = w & 1;                                                      \
    const int lrow = lane & 15;                                                \
    const int kgrp = lane >> 4;                                                \
    const u16* wtA = wtbase;                                                   \
    const u16* wtB = wtbase + 16384;                                           \
    f32x4 accA[4], accB[4];                                                    \
    _Pragma("unroll")                                                          \
    for (int ct = 0; ct < 4; ++ct) {                                           \
        accA[ct] = (f32x4){0.f, 0.f, 0.f, 0.f};                                \
        accB[ct] = (f32x4){0.f, 0.f, 0.f, 0.f};                                \
    }                                                                          \
    _Pragma("unroll")                                                          \
    for (int ks = 0; ks < 4; ++ks) {                                           \
        bf16x8 a = *reinterpret_cast<const bf16x8*>(                           \
            &Xs[rt * 16 + lrow][ks * 32 + kgrp * 8]);                          \
        _Pragma("unroll")                                                      \
        for (int ct = 0; ct < 4; ++ct) {                                       \
            int col = (cg * 4 + ct) * 16 + lrow;                               \
            bf16x8 ba = *reinterpret_cast<const bf16x8*>(                      \
                wtA + ((size_t)col << 7) + ks * 32 + kgrp * 8);                \
            bf16x8 bb = *reinterpret_cast<const bf16x8*>(                      \
                wtB + ((size_t)col << 7) + ks * 32 + kgrp * 8);                \
            accA[ct] = __builtin_amdgcn_mfma_f32_16x16x32_bf16(a, ba, accA[ct], 0, 0, 0);\
            accB[ct] = __builtin_amdgcn_mfma_f32_16x16x32_bf16(a, bb, accB[ct], 0, 0, 0);\
        }                                                                      \
    }                                                                          \
    _Pragma("unroll")                                                          \
    for (int ct = 0; ct < 4; ++ct) {                                           \
        int col = (cg * 4 + ct) * 16 + lrow;                                   \
        float bbv = b1[col];                                                   \
        _Pragma("unroll")                                                      \
        for (int r = 0; r < 4; ++r) {                                          \
            int row = rt * 16 + kgrp * 4 + r;                                  \
            Os[0][row][col] = f2bf(accA[ct][r] + bbv);                         \
            Os[1][row][col] = f2bf(accB[ct][r]);                               \
        }                                                                      \
    }                                                                          \
    __syncthreads();                                                           \
    _Pragma("unroll")                                                          \
    for (int it = 0; it < 4; ++it) {                                           \
        int f = tid + it * 256;        /* 1024 uint4 total */                  \
        int s = f >> 9;                                                        \
        int rem = f & 511;                                                     \
        int r = rem >> 4, c8 = (rem & 15) << 3;                                \
        uint4 vv = *reinterpret_cast<uint4*>(&Os[s][r][c8]);                   \
        u16* dstp = s ? Bm : A;                                                \
        *reinterpret_cast<uint4*>(dstp + (size_t)(br + r) * HID + c8) = vv;    \
    }                                                                          \
    }

// head 0: plain staging -> bf16 LDS
__global__ __launch_bounds__(256) void k_gemm_head(const float* __restrict__ X,
    const u16* __restrict__ wt, const float* __restrict__ b1,
    u16* __restrict__ A, u16* __restrict__ Bm)
{
    __shared__ u16 Xs[HROWS][136];
    __shared__ u16 Os[2][HROWS][136];
    const int tid = threadIdx.x;
    const int br = blockIdx.x * HROWS;
    #pragma unroll
    for (int it = 0; it < 4; ++it) {
        int f = tid + it * 256;          // 1024 chunks: r*32 + cq4
        int r = f >> 5, cq = (f & 31) << 2;
        float4 v = *reinterpret_cast<const float4*>(X + (size_t)(br + r) * HID + cq);
        *reinterpret_cast<uint2*>(&Xs[r][cq]) =
            make_uint2(pack2(v.x, v.y), pack2(v.z, v.w));
    }
    __syncthreads();
    HEAD_MFMA_BODY(wt, b1, A, Bm)
}

// heads 1..L: staging computes x += relu(gin(relu(app(v)))), writes x (+xh),
// stages updated x as bf16 into LDS, then MFMA dual GEMM.
__global__ __launch_bounds__(256) void k_head_resid(const float* __restrict__ v,
    const float* __restrict__ s1, const float* __restrict__ ga, const float* __restrict__ ba,
    const float* __restrict__ s2, const float* __restrict__ gg, const float* __restrict__ bg,
    float* __restrict__ x, u16* __restrict__ xh,
    const u16* __restrict__ wt, const float* __restrict__ b1,
    u16* __restrict__ A, u16* __restrict__ Bm)
{
    __shared__ u16 Xs[HROWS][136];
    __shared__ u16 Os[2][HROWS][136];
    __shared__ float aca[256], acg[256];
    const int tid = threadIdx.x;
    const int br = blockIdx.x * HROWS;
    if (tid < 128) {
        float m = s1[tid] * BN_INV;
        float var = fmaf(-m, m, s1[128 + tid] * BN_INV);
        float a = ga[tid] * rsqrtf(var + 1e-5f);
        aca[tid] = a;
        aca[128 + tid] = fmaf(-m, a, ba[tid]);
        float m2 = s2[tid] * BN_INV;
        float var2 = fmaf(-m2, m2, s2[128 + tid] * BN_INV);
        float a2 = gg[tid] * rsqrtf(var2 + 1e-5f);
        acg[tid] = a2;
        acg[128 + tid] = fmaf(-m2, a2, bg[tid]);
    }
    __syncthreads();
    #pragma unroll
    for (int it = 0; it < 4; ++it) {
        int f = tid + it * 256;
        int r = f >> 5, kq = (f & 31) << 2;
        size_t goff = (size_t)(br + r) * HID + kq;
        float4 vv = *reinterpret_cast<const float4*>(v + goff);
        float4 xv = *reinterpret_cast<const float4*>(x + goff);
        float t0 = fmaxf(fmaf(aca[kq + 0], vv.x, aca[128 + kq + 0]), 0.f);
        float t1 = fmaxf(fmaf(aca[kq + 1], vv.y, aca[128 + kq + 1]), 0.f);
        float t2 = fmaxf(fmaf(aca[kq + 2], vv.z, aca[128 + kq + 2]), 0.f);
        float t3 = fmaxf(fmaf(aca[kq + 3], vv.w, aca[128 + kq + 3]), 0.f);
        xv.x += fmaxf(fmaf(acg[kq + 0], t0, acg[128 + kq + 0]), 0.f);
        xv.y += fmaxf(fmaf(acg[kq + 1], t1, acg[128 + kq + 1]), 0.f);
        xv.z += fmaxf(fmaf(acg[kq + 2], t2, acg[128 + kq + 2]), 0.f);
        xv.w += fmaxf(fmaf(acg[kq + 3], t3, acg[128 + kq + 3]), 0.f);
        *reinterpret_cast<float4*>(x + goff) = xv;
        uint2 p = make_uint2(pack2(xv.x, xv.y), pack2(xv.z, xv.w));
        *reinterpret_cast<uint2*>(xh + goff) = p;
        *reinterpret_cast<uint2*>(&Xs[r][kq]) = p;
    }
    __syncthreads();
    HEAD_MFMA_BODY(wt, b1, A, Bm)
}

// ------------------------------------- stats of relu(app(v)) -> s2
__global__ __launch_bounds__(256) void k_app_stat(const float* __restrict__ v,
    const float* __restrict__ s1, const float* __restrict__ g, const float* __restrict__ b,
    float* __restrict__ s2)
{
    __shared__ float ac[256];
    __shared__ float ls[128], lq[128];
    const int tid = threadIdx.x;
    if (tid < 128) {
        float m = s1[tid] * BN_INV;
        float var = fmaf(-m, m, s1[128 + tid] * BN_INV);
        float a = g[tid] * rsqrtf(var + 1e-5f);
        ac[tid] = a;
        ac[128 + tid] = fmaf(-m, a, b[tid]);
        ls[tid] = 0.f; lq[tid] = 0.f;
    }
    __syncthreads();
    const int j0 = (tid & 31) * 4;
    const int row0 = blockIdx.x * 16 + (tid >> 5);
    float s4[4] = {0.f, 0.f, 0.f, 0.f}, q4[4] = {0.f, 0.f, 0.f, 0.f};
    #pragma unroll
    for (int rr = 0; rr < 2; ++rr) {
        const float4 v4 = *reinterpret_cast<const float4*>(
            v + (size_t)(row0 + rr * 8) * HID + j0);
        float w[4] = {v4.x, v4.y, v4.z, v4.w};
        #pragma unroll
        for (int c = 0; c < 4; ++c) {
            w[c] = fmaxf(fmaf(ac[j0 + c], w[c], ac[128 + j0 + c]), 0.f);
            s4[c] += w[c];
            q4[c] = fmaf(w[c], w[c], q4[c]);
        }
    }
    stat_reduce4(s4, q4, j0, ls, lq, s2);
}

// ---------------------------------------------------- edge head (dst-CSR)
__global__ __launch_bounds__(256) void k_edge_csr(const u16* __restrict__ Ah,
    const u16* __restrict__ Bh, const int* __restrict__ off,
    const u16* __restrict__ eidx, const int* __restrict__ epos,
    const float* __restrict__ w2, const float* __restrict__ b2,
    float* __restrict__ out, int accumulate)
{
    const int wid = (blockIdx.x * 256 + threadIdx.x) >> 6;
    const int lane = threadIdx.x & 63;
    const int q = lane >> 4, l = lane & 15;
    const int start = wid ? off[wid - 1] : 0;
    const int end = off[wid];
    const uint4 bb = *reinterpret_cast<const uint4*>(Bh + (size_t)wid * HID + l * 8);
    float b8[8] = {bf2f(bb.x & 0xffff), bf2f(bb.x >> 16),
                   bf2f(bb.y & 0xffff), bf2f(bb.y >> 16),
                   bf2f(bb.z & 0xffff), bf2f(bb.z >> 16),
                   bf2f(bb.w & 0xffff), bf2f(bb.w >> 16)};
    float w2f[16];
    #pragma unroll
    for (int t = 0; t < 4; ++t)
        *reinterpret_cast<float4*>(&w2f[t * 4]) =
            *reinterpret_cast<const float4*>(w2 + l * 16 + t * 4);
    const float bias0 = b2[0], bias1 = b2[1];
    for (int e = start + q; e < end; e += 4) {
        int s = eidx[e];
        const uint4 aa = *reinterpret_cast<const uint4*>(Ah + (size_t)s * HID + l * 8);
        float a8[8] = {bf2f(aa.x & 0xffff), bf2f(aa.x >> 16),
                       bf2f(aa.y & 0xffff), bf2f(aa.y >> 16),
                       bf2f(aa.z & 0xffff), bf2f(aa.z >> 16),
                       bf2f(aa.w & 0xffff), bf2f(aa.w >> 16)};
        float s0 = 0.f, s1 = 0.f;
        #pragma unroll
        for (int j = 0; j < 8; ++j) {
            float z = fmaxf(a8[j] + b8[j], 0.f);
            s0 = fmaf(z, w2f[j * 2], s0);
            s1 = fmaf(z, w2f[j * 2 + 1], s1);
        }
        #pragma unroll
        for (int m = 8; m >= 1; m >>= 1) {
            s0 += __shfl_xor(s0, m);
            s1 += __shfl_xor(s1, m);
        }
        if (l == 0) {
            int oe = epos[e];
            float o0 = s0 + bias0, o1 = s1 + bias1;
            if (accumulate) {
                out[oe * 2 + 0] += o0;
                out[oe * 2 + 1] += o1;
            } else {
                out[oe * 2 + 0] = o0;
                out[oe * 2 + 1] = o1;
            }
        }
    }
}

// ------------------------- merged edge head + gather (one CSR pass)
__global__ __launch_bounds__(256) void k_edge_gather(const u16* __restrict__ Ah,
    const u16* __restrict__ Bh, const float* __restrict__ x,
    const u16* __restrict__ xh, const int* __restrict__ off,
    const u16* __restrict__ eidx, const int* __restrict__ epos,
    const float* __restrict__ w2, const float* __restrict__ b2,
    float* __restrict__ out, int accumulate,
    const float* __restrict__ eps, int layer, float* __restrict__ t)
{
    const int wid = (blockIdx.x * 256 + threadIdx.x) >> 6;
    const int lane = threadIdx.x & 63;
    const int q = lane >> 4, l = lane & 15;
    const int start = wid ? off[wid - 1] : 0;
    const int end = off[wid];
    const uint4 bb = *reinterpret_cast<const uint4*>(Bh + (size_t)wid * HID + l * 8);
    float b8[8] = {bf2f(bb.x & 0xffff), bf2f(bb.x >> 16),
                   bf2f(bb.y & 0xffff), bf2f(bb.y >> 16),
                   bf2f(bb.z & 0xffff), bf2f(bb.z >> 16),
                   bf2f(bb.w & 0xffff), bf2f(bb.w >> 16)};
    float w2f[16];
    #pragma unroll
    for (int tt = 0; tt < 4; ++tt)
        *reinterpret_cast<float4*>(&w2f[tt * 4]) =
            *reinterpret_cast<const float4*>(w2 + l * 16 + tt * 4);
    const float bias0 = b2[0], bias1 = b2[1];
    float g8[8] = {0.f, 0.f, 0.f, 0.f, 0.f, 0.f, 0.f, 0.f};

    #define EG_BODY(EE)                                                        \
    {                                                                          \
        int s = eidx[EE];                                                      \
        const uint4 aa = *reinterpret_cast<const uint4*>(Ah + (size_t)s * HID + l * 8);\
        const uint4 gv = *reinterpret_cast<const uint4*>(xh + (size_t)s * HID + l * 8);\
        g8[0] += bf2f(gv.x & 0xffff); g8[1] += bf2f(gv.x >> 16);               \
        g8[2] += bf2f(gv.y & 0xffff); g8[3] += bf2f(gv.y >> 16);               \
        g8[4] += bf2f(gv.z & 0xffff); g8[5] += bf2f(gv.z >> 16);               \
        g8[6] += bf2f(gv.w & 0xffff); g8[7] += bf2f(gv.w >> 16);               \
        float a8[8] = {bf2f(aa.x & 0xffff), bf2f(aa.x >> 16),                  \
                       bf2f(aa.y & 0xffff), bf2f(aa.y >> 16),                  \
                       bf2f(aa.z & 0xffff), bf2f(aa.z >> 16),                  \
                       bf2f(aa.w & 0xffff), bf2f(aa.w >> 16)};                 \
        float s0 = 0.f, s1 = 0.f;                                              \
        _Pragma("unroll")                                                      \
        for (int j = 0; j < 8; ++j) {                                          \
            float z = fmaxf(a8[j] + b8[j], 0.f);                               \
            s0 = fmaf(z, w2f[j * 2], s0);                                      \
            s1 = fmaf(z, w2f[j * 2 + 1], s1);                                  \
        }                                                                      \
        _Pragma("unroll")                                                      \
        for (int m = 8; m >= 1; m >>= 1) {                                     \
            s0 += __shfl_xor(s0, m);                                           \
            s1 += __shfl_xor(s1, m);                                           \
        }                                                                      \
        if (l == 0) {                                                          \
            int oe = epos[EE];                                                 \
            float o0 = s0 + bias0, o1 = s1 + bias1;                            \
            if (accumulate) { out[oe * 2] += o0; out[oe * 2 + 1] += o1; }      \
            else            { out[oe * 2]  = o0; out[oe * 2 + 1]  = o1; }      \
        }                                                                      \
    }

    int e = start + q;
    for (; e + 4 < end; e += 8) {
        EG_BODY(e)
        EG_BODY(e + 4)
    }
    if (e < end) EG_BODY(e)
    #undef EG_BODY

    #pragma unroll
    for (int j = 0; j < 8; ++j) {
        g8[j] += __shfl_xor(g8[j], 16);
        g8[j] += __shfl_xor(g8[j], 32);
    }
    if (q == 0) {
        const float e1 = 1.0f + eps[layer];
        const float4* xr = reinterpret_cast<const float4*>(x + (size_t)wid * HID + l * 8);
        float4 a0 = xr[0], a1 = xr[1];
        float4* tw = reinterpret_cast<float4*>(t + (size_t)wid * HID + l * 8);
        tw[0] = make_float4(fmaf(a0.x, e1, g8[0]), fmaf(a0.y, e1, g8[1]),
                            fmaf(a0.z, e1, g8[2]), fmaf(a0.w, e1, g8[3]));
        tw[1] = make_float4(fmaf(a1.x, e1, g8[4]), fmaf(a1.y, e1, g8[5]),
                            fmaf(a1.z, e1, g8[6]), fmaf(a1.w, e1, g8[7]));
    }
}

// ---------------------------------------------------------------- launch
extern "C" void kernel_launch(void* const* d_in, const int* in_sizes, int n_in,
                              void* d_out, int out_size, void* d_ws, size_t ws_size,
                              hipStream_t stream)
{
    const float* h        = (const float*)d_in[0];
    const int*   src      = (const int*)d_in[1];
    const int*   dst      = (const int*)d_in[2];
    const float* emb_w    = (const float*)d_in[3];
    const float* emb_b    = (const float*)d_in[4];
    const float* eps      = (const float*)d_in[5];
    const float* mlp_w1   = (const float*)d_in[6];
    const float* mlp_b1   = (const float*)d_in[7];
    const float* mlp_bn_g = (const float*)d_in[8];
    const float* mlp_bn_b = (const float*)d_in[9];
    const float* mlp_w2   = (const float*)d_in[10];
    const float* mlp_b2   = (const float*)d_in[11];
    const float* app_bn_g = (const float*)d_in[12];
    const float* app_bn_b = (const float*)d_in[13];
    const float* gin_bn_g = (const float*)d_in[14];
    const float* gin_bn_b = (const float*)d_in[15];
    const float* pred_w1  = (const float*)d_in[16];
    const float* pred_b1  = (const float*)d_in[17];
    const float* pred_w2  = (const float*)d_in[18];
    const float* pred_b2  = (const float*)d_in[19];
    float* out = (float*)d_out;

    float* ws   = (float*)d_ws;
    float* x    = ws;                       // [N,128] f32
    float* tmp1 = ws + NH;                  // [N,128] f32 (t / v)
    float* tmp2 = ws + 2 * (size_t)NH;      // [N,128] f32 (u), aliased by bf16 A,B
    float* sums = ws + 3 * (size_t)NH;      // [12][256]
    int*   off  = (int*)(sums + 12 * 256);  // [N]
    int*   deg  = off + NNODES;             // [N]
    int*   epos = deg + NNODES;             // [E]
    u16*   eidx = (u16*)(epos + NEDGES);    // [E]
    u16*   ah   = (u16*)tmp2;               // [N,128] bf16
    u16*   bh   = ah + NH;                  // [N,128] bf16
    u16*   xh   = eidx + NEDGES;            // [N,128] bf16 shadow of x
    u16*   wt   = xh + NH;                  // [5][2][128][128] bf16 transposed W1

    const int NB = NH / 256;                    // 10000
    const int EB = NEDGES / 256;                // 1250
    const int GB = NNODES / ROWS;               // 500 (MLP GEMMs)
    const int HB = NNODES / HROWS;              // 625 (head MFMA GEMMs)
    const int ASB = NNODES / 16;                // 1250
    const int CEB = NNODES / 4;                 // 5000
    const int WTB = 5 * 2 * 128 * 128 / 256;    // 640

    // ---- CSR build + weight transpose (once)
    hipMemsetAsync(deg, 0, NNODES * sizeof(int), stream);
    hipMemsetAsync(sums, 0, 12 * 256 * sizeof(float), stream);
    k_hist<<<EB, 256, 0, stream>>>(dst, deg);
    k_scan<<<1, 1024, 0, stream>>>(deg, off);
    k_fill<<<EB, 256, 0, stream>>>(src, dst, off, eidx, epos);
    k_wt<<<WTB, 256, 0, stream>>>(pred_w1, wt);

    k_embed<<<NB, 256, 0, stream>>>(h, emb_w, emb_b, x, xh);

    // head 0 GEMM (MFMA)
    k_gemm_head<<<HB, 256, 0, stream>>>(x, wt, pred_b1, ah, bh);

    for (int i = 0; i < NL; ++i) {
        float* s0 = sums + (i * 3 + 0) * 256;
        float* s1 = sums + (i * 3 + 1) * 256;
        float* s2 = sums + (i * 3 + 2) * 256;

        // merged: edge scores for head i  +  t = (1+eps)x + sum xh[src]
        k_edge_gather<<<CEB, 256, 0, stream>>>(ah, bh, x, xh, off, eidx, epos,
                                               pred_w2 + i * HID * 2,
                                               pred_b2 + i * 2, out, (i > 0),
                                               eps, i, tmp1);

        // u = t @ W1 + b1 ; stats(u) -> s0
        k_gemm_stat<<<GB, 256, 0, stream>>>(tmp1, mlp_w1 + (size_t)i * HID * HID,
                                            mlp_b1 + i * HID, tmp2, s0);
        // v = relu(BN_s0(u)) @ W2 + b2 ; stats(v) -> s1
        k_gemm_bnin_stat<<<GB, 256, 0, stream>>>(tmp2, s0, mlp_bn_g + i * HID,
                                                 mlp_bn_b + i * HID,
                                                 mlp_w2 + (size_t)i * HID * HID,
                                                 mlp_b2 + i * HID, tmp1, s1);
        // stats(relu(BN_s1(v))) -> s2
        k_app_stat<<<ASB, 256, 0, stream>>>(tmp1, s1, app_bn_g + i * HID,
                                            app_bn_b + i * HID, s2);
        // x += relu(BN_s2(relu(BN_s1(v)))) fused into MFMA head GEMM staging
        k_head_resid<<<HB, 256, 0, stream>>>(tmp1, s1, app_bn_g + i * HID,
                                             app_bn_b + i * HID, s2,
                                             gin_bn_g + i * HID, gin_bn_b + i * HID,
                                             x, xh,
                                             wt + (size_t)(i + 1) * 2 * 128 * 128,
                                             pred_b1 + (i + 1) * HID, ah, bh);
    }
    // last head's edge scores
    k_edge_csr<<<CEB, 256, 0, stream>>>(ah, bh, off, eidx, epos,
                                        pred_w2 + NL * HID * 2,
                                        pred_b2 + NL * 2, out, 1);
}

// Round 12
// 730.617 us; speedup vs baseline: 1.2739x; 1.0444x over previous
//
#include <hip/hip_runtime.h>

#define NNODES 20000
#define NEDGES 320000
#define HID 128
#define NL 4

constexpr int NH = NNODES * HID;
#define BN_INV (1.0f / (float)NNODES)
#define HROWS 32         // MFMA GEMM rows/block; 625 blocks

typedef unsigned short u16;
typedef unsigned int u32;
typedef __attribute__((ext_vector_type(8))) short bf16x8;
typedef __attribute__((ext_vector_type(8))) _Float16 f16x8;
typedef __attribute__((ext_vector_type(4))) float f32x4;

// ---------------------------------------------------------------- bf16 utils
__device__ __forceinline__ float bf2f(u32 lo16) {
    union { u32 u; float f; } c; c.u = lo16 << 16; return c.f;
}
__device__ __forceinline__ u16 f2bf(float f) {
    union { float f; u32 u; } c; c.f = f;
    u32 r = c.u + 0x7FFFu + ((c.u >> 16) & 1u);
    return (u16)(r >> 16);
}
__device__ __forceinline__ u32 pack2(float a, float b) {
    return (u32)f2bf(a) | ((u32)f2bf(b) << 16);
}

// ---------------------------------------------------------------- embed
__global__ __launch_bounds__(256) void k_embed(const float* __restrict__ h,
    const float* __restrict__ ew, const float* __restrict__ eb,
    float* __restrict__ x, u16* __restrict__ xh)
{
    int i = blockIdx.x * 256 + threadIdx.x;          // exactly NH threads
    int nrow = i >> 7, j = i & 127;
    float v = fmaf(h[nrow * 2], ew[j], fmaf(h[nrow * 2 + 1], ew[HID + j], eb[j]));
    x[i] = v;
    xh[i] = f2bf(v);
}

// ------------------------------------------ one-time bf16 head-weight transpose
// wt[h][s][c][k] = pred_w1[h][s*128+k][c]; 5*2*128*128 elements
__global__ __launch_bounds__(256) void k_wt(const float* __restrict__ pw1,
    u16* __restrict__ wt)
{
    int i = blockIdx.x * 256 + threadIdx.x;          // 640 blocks
    int k = i & 127;
    int c = (i >> 7) & 127;
    int sh = i >> 14;                                // h*2+s
    wt[i] = f2bf(pw1[(size_t)(sh >> 1) * 256 * 128 + (((sh & 1) * 128 + k) << 7) + c]);
}

// ------------------------------------------ one-time fp16 MLP-weight transpose
// wtm[layer][which][c][k] = W[layer][k][c]; 4*2*128*128 elements
__global__ __launch_bounds__(256) void k_wtm(const float* __restrict__ w1,
    const float* __restrict__ w2, u16* __restrict__ wtm)
{
    int i = blockIdx.x * 256 + threadIdx.x;          // 512 blocks
    int k = i & 127;
    int c = (i >> 7) & 127;
    int lw = i >> 14;                                // layer*2+which
    const float* wsrc = (lw & 1) ? w2 : w1;
    float v = wsrc[(size_t)(lw >> 1) * 16384 + (k << 7) + c];
    union { _Float16 h; u16 u; } cv; cv.h = (_Float16)v;
    wtm[i] = cv.u;
}

// ---------------------------------------------------------------- CSR build
__global__ __launch_bounds__(256) void k_hist(const int* __restrict__ dst,
    int* __restrict__ deg)
{
    int e = blockIdx.x * 256 + threadIdx.x;
    atomicAdd(&deg[dst[e]], 1);
}

__global__ __launch_bounds__(1024) void k_scan(const int* __restrict__ deg,
    int* __restrict__ off)
{
    __shared__ int part[1024];
    const int t = threadIdx.x;
    const int lo = t * 20, hi = min(lo + 20, NNODES);
    int s = 0;
    for (int i = lo; i < hi; ++i) s += deg[i];
    part[t] = s;
    __syncthreads();
    for (int d = 1; d < 1024; d <<= 1) {
        int v = (t >= d) ? part[t - d] : 0;
        __syncthreads();
        part[t] += v;
        __syncthreads();
    }
    int base = part[t] - s;
    for (int i = lo; i < hi; ++i) { off[i] = base; base += deg[i]; }
}

__global__ __launch_bounds__(256) void k_fill(const int* __restrict__ src,
    const int* __restrict__ dst, int* __restrict__ off,
    u16* __restrict__ eidx, int* __restrict__ epos)
{
    int e = blockIdx.x * 256 + threadIdx.x;
    int p = atomicAdd(&off[dst[e]], 1);
    eidx[p] = (u16)src[e];
    epos[p] = e;
}

// --------------------------------------------- stat helper (k_app_stat)
__device__ __forceinline__ void stat_reduce4(float* s4, float* q4, int j0,
    float* ls, float* lq, float* sums)
{
    const int lane = threadIdx.x & 63;
    #pragma unroll
    for (int c = 0; c < 4; ++c) {
        s4[c] += __shfl_xor(s4[c], 32);
        q4[c] += __shfl_xor(q4[c], 32);
    }
    if (lane < 32) {
        #pragma unroll
        for (int c = 0; c < 4; ++c) {
            atomicAdd(&ls[j0 + c], s4[c]);
            atomicAdd(&lq[j0 + c], q4[c]);
        }
    }
    __syncthreads();
    if (threadIdx.x < 128) {
        atomicAdd(&sums[threadIdx.x], ls[threadIdx.x]);
        atomicAdd(&sums[128 + threadIdx.x], lq[threadIdx.x]);
    }
}

// -------------------------------------- MFMA MLP GEMM core (single matrix)
// Xs fp16 [32][136]; wtm fp16 [128][128] (c-major rows, k contiguous).
// 4 waves: rt=w>>1 (16-row tile), cg=w&1 (64-col half). Epilogue: bias, f32
// C via LDS, per-column stats via shfl over kgrp + LDS atomics.
#define MLP_MFMA_TAIL(wtm16, bias, Cm, sums)                                   \
    {                                                                          \
    const int w = tid >> 6;                                                    \
    const int lane = tid & 63;                                                 \
    const int rt = w >> 1;                                                     \
    const int cg = w & 1;                                                      \
    const int lrow = lane & 15;                                                \
    const int kgrp = lane >> 4;                                                \
    f32x4 acc[4];                                                              \
    _Pragma("unroll")                                                          \
    for (int ct = 0; ct < 4; ++ct) acc[ct] = (f32x4){0.f, 0.f, 0.f, 0.f};      \
    _Pragma("unroll")                                                          \
    for (int ks = 0; ks < 4; ++ks) {                                           \
        f16x8 a = *reinterpret_cast<const f16x8*>(                             \
            &Xs[rt * 16 + lrow][ks * 32 + kgrp * 8]);                          \
        _Pragma("unroll")                                                      \
        for (int ct = 0; ct < 4; ++ct) {                                       \
            int col = (cg * 4 + ct) * 16 + lrow;                               \
            f16x8 b = *reinterpret_cast<const f16x8*>(                         \
                wtm16 + ((size_t)col << 7) + ks * 32 + kgrp * 8);              \
            acc[ct] = __builtin_amdgcn_mfma_f32_16x16x32_f16(a, b, acc[ct], 0, 0, 0);\
        }                                                                      \
    }                                                                          \
    _Pragma("unroll")                                                          \
    for (int ct = 0; ct < 4; ++ct) {                                           \
        int col = (cg * 4 + ct) * 16 + lrow;                                   \
        float bbv = bias[col];                                                 \
        float s = 0.f, q = 0.f;                                                \
        _Pragma("unroll")                                                      \
        for (int r = 0; r < 4; ++r) {                                          \
            float val = acc[ct][r] + bbv;                                      \
            Os[rt * 16 + kgrp * 4 + r][col] = val;                             \
            s += val;                                                          \
            q = fmaf(val, val, q);                                             \
        }                                                                      \
        s += __shfl_xor(s, 16); s += __shfl_xor(s, 32);                        \
        q += __shfl_xor(q, 16); q += __shfl_xor(q, 32);                        \
        if (kgrp == 0) { atomicAdd(&ls[col], s); atomicAdd(&lq[col], q); }     \
    }                                                                          \
    __syncthreads();                                                           \
    _Pragma("unroll")                                                          \
    for (int it = 0; it < 4; ++it) {                                           \
        int f = tid + it * 256;                                                \
        int r = f >> 5, c4 = (f & 31) << 2;                                    \
        *reinterpret_cast<float4*>(Cm + (size_t)(br + r) * HID + c4) =         \
            *reinterpret_cast<const float4*>(&Os[r][c4]);                      \
    }                                                                          \
    if (tid < 128) {                                                           \
        atomicAdd(&sums[tid], ls[tid]);                                        \
        atomicAdd(&sums[128 + tid], lq[tid]);                                  \
    }                                                                          \
    }

// u = t @ W1 + b1 ; stats(u)
__global__ __launch_bounds__(256) void k_mfma_stat(const float* __restrict__ X,
    const u16* __restrict__ wtm, const float* __restrict__ bias,
    float* __restrict__ Cm, float* __restrict__ sums)
{
    __shared__ _Float16 Xs[HROWS][136];
    __shared__ float Os[HROWS][132];
    __shared__ float ls[128], lq[128];
    const int tid = threadIdx.x;
    const int br = blockIdx.x * HROWS;
    if (tid < 128) { ls[tid] = 0.f; lq[tid] = 0.f; }
    #pragma unroll
    for (int it = 0; it < 4; ++it) {
        int f = tid + it * 256;
        int r = f >> 5, kq = (f & 31) << 2;
        float4 v = *reinterpret_cast<const float4*>(X + (size_t)(br + r) * HID + kq);
        union { _Float16 h[4]; uint2 u; } p;
        p.h[0] = (_Float16)v.x; p.h[1] = (_Float16)v.y;
        p.h[2] = (_Float16)v.z; p.h[3] = (_Float16)v.w;
        *reinterpret_cast<uint2*>(&Xs[r][kq]) = p.u;
    }
    __syncthreads();
    const _Float16* wtm16 = reinterpret_cast<const _Float16*>(wtm);
    MLP_MFMA_TAIL(wtm16, bias, Cm, sums)
}

// v = relu(BN_sIn(u)) @ W2 + b2 ; stats(v)
__global__ __launch_bounds__(256) void k_mfma_bnin_stat(const float* __restrict__ X,
    const float* __restrict__ sIn, const float* __restrict__ g, const float* __restrict__ b,
    const u16* __restrict__ wtm, const float* __restrict__ bias,
    float* __restrict__ Cm, float* __restrict__ sums)
{
    __shared__ _Float16 Xs[HROWS][136];
    __shared__ float Os[HROWS][132];
    __shared__ float ac[256];
    __shared__ float ls[128], lq[128];
    const int tid = threadIdx.x;
    const int br = blockIdx.x * HROWS;
    if (tid < 128) {
        float m = sIn[tid] * BN_INV;
        float var = fmaf(-m, m, sIn[128 + tid] * BN_INV);
        float a = g[tid] * rsqrtf(var + 1e-5f);
        ac[tid] = a;
        ac[128 + tid] = fmaf(-m, a, b[tid]);
        ls[tid] = 0.f; lq[tid] = 0.f;
    }
    __syncthreads();
    #pragma unroll
    for (int it = 0; it < 4; ++it) {
        int f = tid + it * 256;
        int r = f >> 5, kq = (f & 31) << 2;
        float4 v = *reinterpret_cast<const float4*>(X + (size_t)(br + r) * HID + kq);
        float t0 = fmaxf(fmaf(ac[kq + 0], v.x, ac[128 + kq + 0]), 0.f);
        float t1 = fmaxf(fmaf(ac[kq + 1], v.y, ac[128 + kq + 1]), 0.f);
        float t2 = fmaxf(fmaf(ac[kq + 2], v.z, ac[128 + kq + 2]), 0.f);
        float t3 = fmaxf(fmaf(ac[kq + 3], v.w, ac[128 + kq + 3]), 0.f);
        union { _Float16 h[4]; uint2 u; } p;
        p.h[0] = (_Float16)t0; p.h[1] = (_Float16)t1;
        p.h[2] = (_Float16)t2; p.h[3] = (_Float16)t3;
        *reinterpret_cast<uint2*>(&Xs[r][kq]) = p.u;
    }
    __syncthreads();
    const _Float16* wtm16 = reinterpret_cast<const _Float16*>(wtm);
    MLP_MFMA_TAIL(wtm16, bias, Cm, sums)
}

// ---------------------------------------------- MFMA head GEMM core (shared)
#define HEAD_MFMA_BODY(wtbase, b1, A, Bm)                                      \
    {                                                                          \
    const int w = tid >> 6;                                                    \
    const int lane = tid & 63;                                                 \
    const int rt = w >> 1;                                                     \
    const int cg = w & 1;                                                      \
    const int lrow = lane & 15;                                                \
    const int kgrp = lane >> 4;                                                \
    const u16* wtA = wtbase;                                                   \
    const u16* wtB = wtbase + 16384;                                           \
    f32x4 accA[4], accB[4];                                                    \
    _Pragma("unroll")                                                          \
    for (int ct = 0; ct < 4; ++ct) {                                           \
        accA[ct] = (f32x4){0.f, 0.f, 0.f, 0.f};                                \
        accB[ct] = (f32x4){0.f, 0.f, 0.f, 0.f};                                \
    }                                                                          \
    _Pragma("unroll")                                                          \
    for (int ks = 0; ks < 4; ++ks) {                                           \
        bf16x8 a = *reinterpret_cast<const bf16x8*>(                           \
            &Xs[rt * 16 + lrow][ks * 32 + kgrp * 8]);                          \
        _Pragma("unroll")                                                      \
        for (int ct = 0; ct < 4; ++ct) {                                       \
            int col = (cg * 4 + ct) * 16 + lrow;                               \
            bf16x8 ba = *reinterpret_cast<const bf16x8*>(                      \
                wtA + ((size_t)col << 7) + ks * 32 + kgrp * 8);                \
            bf16x8 bb = *reinterpret_cast<const bf16x8*>(                      \
                wtB + ((size_t)col << 7) + ks * 32 + kgrp * 8);                \
            accA[ct] = __builtin_amdgcn_mfma_f32_16x16x32_bf16(a, ba, accA[ct], 0, 0, 0);\
            accB[ct] = __builtin_amdgcn_mfma_f32_16x16x32_bf16(a, bb, accB[ct], 0, 0, 0);\
        }                                                                      \
    }                                                                          \
    _Pragma("unroll")                                                          \
    for (int ct = 0; ct < 4; ++ct) {                                           \
        int col = (cg * 4 + ct) * 16 + lrow;                                   \
        float bbv = b1[col];                                                   \
        _Pragma("unroll")                                                      \
        for (int r = 0; r < 4; ++r) {                                          \
            int row = rt * 16 + kgrp * 4 + r;                                  \
            Os[0][row][col] = f2bf(accA[ct][r] + bbv);                         \
            Os[1][row][col] = f2bf(accB[ct][r]);                               \
        }                                                                      \
    }                                                                          \
    __syncthreads();                                                           \
    _Pragma("unroll")                                                          \
    for (int it = 0; it < 4; ++it) {                                           \
        int f = tid + it * 256;        /* 1024 uint4 total */                  \
        int s = f >> 9;                                                        \
        int rem = f & 511;                                                     \
        int r = rem >> 4, c8 = (rem & 15) << 3;                                \
        uint4 vv = *reinterpret_cast<uint4*>(&Os[s][r][c8]);                   \
        u16* dstp = s ? Bm : A;                                                \
        *reinterpret_cast<uint4*>(dstp + (size_t)(br + r) * HID + c8) = vv;    \
    }                                                                          \
    }

// head 0: plain staging -> bf16 LDS
__global__ __launch_bounds__(256) void k_gemm_head(const float* __restrict__ X,
    const u16* __restrict__ wt, const float* __restrict__ b1,
    u16* __restrict__ A, u16* __restrict__ Bm)
{
    __shared__ u16 Xs[HROWS][136];
    __shared__ u16 Os[2][HROWS][136];
    const int tid = threadIdx.x;
    const int br = blockIdx.x * HROWS;
    #pragma unroll
    for (int it = 0; it < 4; ++it) {
        int f = tid + it * 256;
        int r = f >> 5, cq = (f & 31) << 2;
        float4 v = *reinterpret_cast<const float4*>(X + (size_t)(br + r) * HID + cq);
        *reinterpret_cast<uint2*>(&Xs[r][cq]) =
            make_uint2(pack2(v.x, v.y), pack2(v.z, v.w));
    }
    __syncthreads();
    HEAD_MFMA_BODY(wt, b1, A, Bm)
}

// heads 1..L: staging computes x += relu(gin(relu(app(v)))), writes x (+xh),
// stages updated x as bf16 into LDS, then MFMA dual GEMM.
__global__ __launch_bounds__(256) void k_head_resid(const float* __restrict__ v,
    const float* __restrict__ s1, const float* __restrict__ ga, const float* __restrict__ ba,
    const float* __restrict__ s2, const float* __restrict__ gg, const float* __restrict__ bg,
    float* __restrict__ x, u16* __restrict__ xh,
    const u16* __restrict__ wt, const float* __restrict__ b1,
    u16* __restrict__ A, u16* __restrict__ Bm)
{
    __shared__ u16 Xs[HROWS][136];
    __shared__ u16 Os[2][HROWS][136];
    __shared__ float aca[256], acg[256];
    const int tid = threadIdx.x;
    const int br = blockIdx.x * HROWS;
    if (tid < 128) {
        float m = s1[tid] * BN_INV;
        float var = fmaf(-m, m, s1[128 + tid] * BN_INV);
        float a = ga[tid] * rsqrtf(var + 1e-5f);
        aca[tid] = a;
        aca[128 + tid] = fmaf(-m, a, ba[tid]);
        float m2 = s2[tid] * BN_INV;
        float var2 = fmaf(-m2, m2, s2[128 + tid] * BN_INV);
        float a2 = gg[tid] * rsqrtf(var2 + 1e-5f);
        acg[tid] = a2;
        acg[128 + tid] = fmaf(-m2, a2, bg[tid]);
    }
    __syncthreads();
    #pragma unroll
    for (int it = 0; it < 4; ++it) {
        int f = tid + it * 256;
        int r = f >> 5, kq = (f & 31) << 2;
        size_t goff = (size_t)(br + r) * HID + kq;
        float4 vv = *reinterpret_cast<const float4*>(v + goff);
        float4 xv = *reinterpret_cast<const float4*>(x + goff);
        float t0 = fmaxf(fmaf(aca[kq + 0], vv.x, aca[128 + kq + 0]), 0.f);
        float t1 = fmaxf(fmaf(aca[kq + 1], vv.y, aca[128 + kq + 1]), 0.f);
        float t2 = fmaxf(fmaf(aca[kq + 2], vv.z, aca[128 + kq + 2]), 0.f);
        float t3 = fmaxf(fmaf(aca[kq + 3], vv.w, aca[128 + kq + 3]), 0.f);
        xv.x += fmaxf(fmaf(acg[kq + 0], t0, acg[128 + kq + 0]), 0.f);
        xv.y += fmaxf(fmaf(acg[kq + 1], t1, acg[128 + kq + 1]), 0.f);
        xv.z += fmaxf(fmaf(acg[kq + 2], t2, acg[128 + kq + 2]), 0.f);
        xv.w += fmaxf(fmaf(acg[kq + 3], t3, acg[128 + kq + 3]), 0.f);
        *reinterpret_cast<float4*>(x + goff) = xv;
        uint2 p = make_uint2(pack2(xv.x, xv.y), pack2(xv.z, xv.w));
        *reinterpret_cast<uint2*>(xh + goff) = p;
        *reinterpret_cast<uint2*>(&Xs[r][kq]) = p;
    }
    __syncthreads();
    HEAD_MFMA_BODY(wt, b1, A, Bm)
}

// ------------------------------------- stats of relu(app(v)) -> s2
__global__ __launch_bounds__(256) void k_app_stat(const float* __restrict__ v,
    const float* __restrict__ s1, const float* __restrict__ g, const float* __restrict__ b,
    float* __restrict__ s2)
{
    __shared__ float ac[256];
    __shared__ float ls[128], lq[128];
    const int tid = threadIdx.x;
    if (tid < 128) {
        float m = s1[tid] * BN_INV;
        float var = fmaf(-m, m, s1[128 + tid] * BN_INV);
        float a = g[tid] * rsqrtf(var + 1e-5f);
        ac[tid] = a;
        ac[128 + tid] = fmaf(-m, a, b[tid]);
        ls[tid] = 0.f; lq[tid] = 0.f;
    }
    __syncthreads();
    const int j0 = (tid & 31) * 4;
    const int row0 = blockIdx.x * 16 + (tid >> 5);
    float s4[4] = {0.f, 0.f, 0.f, 0.f}, q4[4] = {0.f, 0.f, 0.f, 0.f};
    #pragma unroll
    for (int rr = 0; rr < 2; ++rr) {
        const float4 v4 = *reinterpret_cast<const float4*>(
            v + (size_t)(row0 + rr * 8) * HID + j0);
        float w[4] = {v4.x, v4.y, v4.z, v4.w};
        #pragma unroll
        for (int c = 0; c < 4; ++c) {
            w[c] = fmaxf(fmaf(ac[j0 + c], w[c], ac[128 + j0 + c]), 0.f);
            s4[c] += w[c];
            q4[c] = fmaf(w[c], w[c], q4[c]);
        }
    }
    stat_reduce4(s4, q4, j0, ls, lq, s2);
}

// ---------------------------------------------------- edge head (dst-CSR)
__global__ __launch_bounds__(256) void k_edge_csr(const u16* __restrict__ Ah,
    const u16* __restrict__ Bh, const int* __restrict__ off,
    const u16* __restrict__ eidx, const int* __restrict__ epos,
    const float* __restrict__ w2, const float* __restrict__ b2,
    float* __restrict__ out, int accumulate)
{
    const int wid = (blockIdx.x * 256 + threadIdx.x) >> 6;
    const int lane = threadIdx.x & 63;
    const int q = lane >> 4, l = lane & 15;
    const int start = wid ? off[wid - 1] : 0;
    const int end = off[wid];
    const uint4 bb = *reinterpret_cast<const uint4*>(Bh + (size_t)wid * HID + l * 8);
    float b8[8] = {bf2f(bb.x & 0xffff), bf2f(bb.x >> 16),
                   bf2f(bb.y & 0xffff), bf2f(bb.y >> 16),
                   bf2f(bb.z & 0xffff), bf2f(bb.z >> 16),
                   bf2f(bb.w & 0xffff), bf2f(bb.w >> 16)};
    float w2f[16];
    #pragma unroll
    for (int t = 0; t < 4; ++t)
        *reinterpret_cast<float4*>(&w2f[t * 4]) =
            *reinterpret_cast<const float4*>(w2 + l * 16 + t * 4);
    const float bias0 = b2[0], bias1 = b2[1];
    for (int e = start + q; e < end; e += 4) {
        int s = eidx[e];
        const uint4 aa = *reinterpret_cast<const uint4*>(Ah + (size_t)s * HID + l * 8);
        float a8[8] = {bf2f(aa.x & 0xffff), bf2f(aa.x >> 16),
                       bf2f(aa.y & 0xffff), bf2f(aa.y >> 16),
                       bf2f(aa.z & 0xffff), bf2f(aa.z >> 16),
                       bf2f(aa.w & 0xffff), bf2f(aa.w >> 16)};
        float s0 = 0.f, s1 = 0.f;
        #pragma unroll
        for (int j = 0; j < 8; ++j) {
            float z = fmaxf(a8[j] + b8[j], 0.f);
            s0 = fmaf(z, w2f[j * 2], s0);
            s1 = fmaf(z, w2f[j * 2 + 1], s1);
        }
        #pragma unroll
        for (int m = 8; m >= 1; m >>= 1) {
            s0 += __shfl_xor(s0, m);
            s1 += __shfl_xor(s1, m);
        }
        if (l == 0) {
            int oe = epos[e];
            float o0 = s0 + bias0, o1 = s1 + bias1;
            if (accumulate) {
                out[oe * 2 + 0] += o0;
                out[oe * 2 + 1] += o1;
            } else {
                out[oe * 2 + 0] = o0;
                out[oe * 2 + 1] = o1;
            }
        }
    }
}

// ------------------------- merged edge head + gather (one CSR pass)
__global__ __launch_bounds__(256) void k_edge_gather(const u16* __restrict__ Ah,
    const u16* __restrict__ Bh, const float* __restrict__ x,
    const u16* __restrict__ xh, const int* __restrict__ off,
    const u16* __restrict__ eidx, const int* __restrict__ epos,
    const float* __restrict__ w2, const float* __restrict__ b2,
    float* __restrict__ out, int accumulate,
    const float* __restrict__ eps, int layer, float* __restrict__ t)
{
    const int wid = (blockIdx.x * 256 + threadIdx.x) >> 6;
    const int lane = threadIdx.x & 63;
    const int q = lane >> 4, l = lane & 15;
    const int start = wid ? off[wid - 1] : 0;
    const int end = off[wid];
    const uint4 bb = *reinterpret_cast<const uint4*>(Bh + (size_t)wid * HID + l * 8);
    float b8[8] = {bf2f(bb.x & 0xffff), bf2f(bb.x >> 16),
                   bf2f(bb.y & 0xffff), bf2f(bb.y >> 16),
                   bf2f(bb.z & 0xffff), bf2f(bb.z >> 16),
                   bf2f(bb.w & 0xffff), bf2f(bb.w >> 16)};
    float w2f[16];
    #pragma unroll
    for (int tt = 0; tt < 4; ++tt)
        *reinterpret_cast<float4*>(&w2f[tt * 4]) =
            *reinterpret_cast<const float4*>(w2 + l * 16 + tt * 4);
    const float bias0 = b2[0], bias1 = b2[1];
    float g8[8] = {0.f, 0.f, 0.f, 0.f, 0.f, 0.f, 0.f, 0.f};

    #define EG_BODY(EE)                                                        \
    {                                                                          \
        int s = eidx[EE];                                                      \
        const uint4 aa = *reinterpret_cast<const uint4*>(Ah + (size_t)s * HID + l * 8);\
        const uint4 gv = *reinterpret_cast<const uint4*>(xh + (size_t)s * HID + l * 8);\
        g8[0] += bf2f(gv.x & 0xffff); g8[1] += bf2f(gv.x >> 16);               \
        g8[2] += bf2f(gv.y & 0xffff); g8[3] += bf2f(gv.y >> 16);               \
        g8[4] += bf2f(gv.z & 0xffff); g8[5] += bf2f(gv.z >> 16);               \
        g8[6] += bf2f(gv.w & 0xffff); g8[7] += bf2f(gv.w >> 16);               \
        float a8[8] = {bf2f(aa.x & 0xffff), bf2f(aa.x >> 16),                  \
                       bf2f(aa.y & 0xffff), bf2f(aa.y >> 16),                  \
                       bf2f(aa.z & 0xffff), bf2f(aa.z >> 16),                  \
                       bf2f(aa.w & 0xffff), bf2f(aa.w >> 16)};                 \
        float s0 = 0.f, s1 = 0.f;                                              \
        _Pragma("unroll")                                                      \
        for (int j = 0; j < 8; ++j) {                                          \
            float z = fmaxf(a8[j] + b8[j], 0.f);                               \
            s0 = fmaf(z, w2f[j * 2], s0);                                      \
            s1 = fmaf(z, w2f[j * 2 + 1], s1);                                  \
        }                                                                      \
        _Pragma("unroll")                                                      \
        for (int m = 8; m >= 1; m >>= 1) {                                     \
            s0 += __shfl_xor(s0, m);                                           \
            s1 += __shfl_xor(s1, m);                                           \
        }                                                                      \
        if (l == 0) {                                                          \
            int oe = epos[EE];                                                 \
            float o0 = s0 + bias0, o1 = s1 + bias1;                            \
            if (accumulate) { out[oe * 2] += o0; out[oe * 2 + 1] += o1; }      \
            else            { out[oe * 2]  = o0; out[oe * 2 + 1]  = o1; }      \
        }                                                                      \
    }

    int e = start + q;
    for (; e + 4 < end; e += 8) {
        EG_BODY(e)
        EG_BODY(e + 4)
    }
    if (e < end) EG_BODY(e)
    #undef EG_BODY

    #pragma unroll
    for (int j = 0; j < 8; ++j) {
        g8[j] += __shfl_xor(g8[j], 16);
        g8[j] += __shfl_xor(g8[j], 32);
    }
    if (q == 0) {
        const float e1 = 1.0f + eps[layer];
        const float4* xr = reinterpret_cast<const float4*>(x + (size_t)wid * HID + l * 8);
        float4 a0 = xr[0], a1 = xr[1];
        float4* tw = reinterpret_cast<float4*>(t + (size_t)wid * HID + l * 8);
        tw[0] = make_float4(fmaf(a0.x, e1, g8[0]), fmaf(a0.y, e1, g8[1]),
                            fmaf(a0.z, e1, g8[2]), fmaf(a0.w, e1, g8[3]));
        tw[1] = make_float4(fmaf(a1.x, e1, g8[4]), fmaf(a1.y, e1, g8[5]),
                            fmaf(a1.z, e1, g8[6]), fmaf(a1.w, e1, g8[7]));
    }
}

// ---------------------------------------------------------------- launch
extern "C" void kernel_launch(void* const* d_in, const int* in_sizes, int n_in,
                              void* d_out, int out_size, void* d_ws, size_t ws_size,
                              hipStream_t stream)
{
    const float* h        = (const float*)d_in[0];
    const int*   src      = (const int*)d_in[1];
    const int*   dst      = (const int*)d_in[2];
    const float* emb_w    = (const float*)d_in[3];
    const float* emb_b    = (const float*)d_in[4];
    const float* eps      = (const float*)d_in[5];
    const float* mlp_w1   = (const float*)d_in[6];
    const float* mlp_b1   = (const float*)d_in[7];
    const float* mlp_bn_g = (const float*)d_in[8];
    const float* mlp_bn_b = (const float*)d_in[9];
    const float* mlp_w2   = (const float*)d_in[10];
    const float* mlp_b2   = (const float*)d_in[11];
    const float* app_bn_g = (const float*)d_in[12];
    const float* app_bn_b = (const float*)d_in[13];
    const float* gin_bn_g = (const float*)d_in[14];
    const float* gin_bn_b = (const float*)d_in[15];
    const float* pred_w1  = (const float*)d_in[16];
    const float* pred_b1  = (const float*)d_in[17];
    const float* pred_w2  = (const float*)d_in[18];
    const float* pred_b2  = (const float*)d_in[19];
    float* out = (float*)d_out;

    float* ws   = (float*)d_ws;
    float* x    = ws;                       // [N,128] f32
    float* tmp1 = ws + NH;                  // [N,128] f32 (t / v)
    float* tmp2 = ws + 2 * (size_t)NH;      // [N,128] f32 (u), aliased by bf16 A,B
    float* sums = ws + 3 * (size_t)NH;      // [12][256]
    int*   off  = (int*)(sums + 12 * 256);  // [N]
    int*   deg  = off + NNODES;             // [N]
    int*   epos = deg + NNODES;             // [E]
    u16*   eidx = (u16*)(epos + NEDGES);    // [E]
    u16*   ah   = (u16*)tmp2;               // [N,128] bf16
    u16*   bh   = ah + NH;                  // [N,128] bf16
    u16*   xh   = eidx + NEDGES;            // [N,128] bf16 shadow of x
    u16*   wt   = xh + NH;                  // [5][2][128][128] bf16 head weights^T
    u16*   wtm  = wt + 5 * 2 * 128 * 128;   // [4][2][128][128] fp16 MLP weights^T

    const int NB = NH / 256;                    // 10000
    const int EB = NEDGES / 256;                // 1250
    const int HB = NNODES / HROWS;              // 625 (all MFMA GEMMs)
    const int ASB = NNODES / 16;                // 1250
    const int CEB = NNODES / 4;                 // 5000
    const int WTB = 5 * 2 * 128 * 128 / 256;    // 640
    const int WMB = 4 * 2 * 128 * 128 / 256;    // 512

    // ---- CSR build + weight transposes (once)
    hipMemsetAsync(deg, 0, NNODES * sizeof(int), stream);
    hipMemsetAsync(sums, 0, 12 * 256 * sizeof(float), stream);
    k_hist<<<EB, 256, 0, stream>>>(dst, deg);
    k_scan<<<1, 1024, 0, stream>>>(deg, off);
    k_fill<<<EB, 256, 0, stream>>>(src, dst, off, eidx, epos);
    k_wt<<<WTB, 256, 0, stream>>>(pred_w1, wt);
    k_wtm<<<WMB, 256, 0, stream>>>(mlp_w1, mlp_w2, wtm);

    k_embed<<<NB, 256, 0, stream>>>(h, emb_w, emb_b, x, xh);

    // head 0 GEMM (MFMA)
    k_gemm_head<<<HB, 256, 0, stream>>>(x, wt, pred_b1, ah, bh);

    for (int i = 0; i < NL; ++i) {
        float* s0 = sums + (i * 3 + 0) * 256;
        float* s1 = sums + (i * 3 + 1) * 256;
        float* s2 = sums + (i * 3 + 2) * 256;

        // merged: edge scores for head i  +  t = (1+eps)x + sum xh[src]
        k_edge_gather<<<CEB, 256, 0, stream>>>(ah, bh, x, xh, off, eidx, epos,
                                               pred_w2 + i * HID * 2,
                                               pred_b2 + i * 2, out, (i > 0),
                                               eps, i, tmp1);

        // u = t @ W1 + b1 ; stats(u) -> s0   (fp16 MFMA)
        k_mfma_stat<<<HB, 256, 0, stream>>>(tmp1, wtm + (size_t)(i * 2 + 0) * 16384,
                                            mlp_b1 + i * HID, tmp2, s0);
        // v = relu(BN_s0(u)) @ W2 + b2 ; stats(v) -> s1   (fp16 MFMA)
        k_mfma_bnin_stat<<<HB, 256, 0, stream>>>(tmp2, s0, mlp_bn_g + i * HID,
                                                 mlp_bn_b + i * HID,
                                                 wtm + (size_t)(i * 2 + 1) * 16384,
                                                 mlp_b2 + i * HID, tmp1, s1);
        // stats(relu(BN_s1(v))) -> s2
        k_app_stat<<<ASB, 256, 0, stream>>>(tmp1, s1, app_bn_g + i * HID,
                                            app_bn_b + i * HID, s2);
        // x += relu(BN_s2(relu(BN_s1(v)))) fused into MFMA head GEMM staging
        k_head_resid<<<HB, 256, 0, stream>>>(tmp1, s1, app_bn_g + i * HID,
                                             app_bn_b + i * HID, s2,
                                             gin_bn_g + i * HID, gin_bn_b + i * HID,
                                             x, xh,
                                             wt + (size_t)(i + 1) * 2 * 128 * 128,
                                             pred_b1 + (i + 1) * HID, ah, bh);
    }
    // last head's edge scores
    k_edge_csr<<<CEB, 256, 0, stream>>>(ah, bh, off, eidx, epos,
                                        pred_w2 + NL * HID * 2,
                                        pred_b2 + NL * 2, out, 1);
}